// Round 14
// baseline (343.700 us; speedup 1.0000x reference)
//
#include <hip/hip_runtime.h>
#include <math.h>

__device__ __forceinline__ float silu(float x) { return x / (1.0f + __expf(-x)); }

typedef __attribute__((ext_vector_type(8))) short short8v;  // 8 bf16 (4 VGPRs)
typedef __attribute__((ext_vector_type(4))) float f32x4;

__device__ __forceinline__ unsigned short f2bf(float x) {
  unsigned int u = __float_as_uint(x);
  return (unsigned short)((u + 0x8000u) >> 16);
}

// ---------------- Kernel 1: node precompute, 16 nodes/block, LDS weights ---
// Flat (node, output) mapping: 16 nodes x 288 outputs = 18 passes x 256 thr.
// One barrier total; weights read from LDS (L2 traffic /16).
__global__ __launch_bounds__(256) void node_pre_kernel(
    const float* __restrict__ nf, const float* __restrict__ na,
    const float* __restrict__ w0, const float* __restrict__ w1,
    const float* __restrict__ scw0, const float* __restrict__ scw1,
    float* __restrict__ y, float* __restrict__ sc, int N)
{
  __shared__ float sW0[1024];       // lin1_w0 [32][32]
  __shared__ float sW1[1024];       // lin1_w1 [32][32]
  __shared__ float sS0[8192];       // sc_w0 [128][64]
  __shared__ float sS1[4096];       // sc_w1 [128][32]
  __shared__ float snd[16 * 132];   // per-node nf[128] + na[4], stride 132
  const int t = threadIdx.x;
  const int n0 = blockIdx.x * 16;

  for (int x = t; x < 1024; x += 256) { sW0[x] = w0[x]; sW1[x] = w1[x]; }
  for (int x = t; x < 8192; x += 256) sS0[x] = scw0[x];
  for (int x = t; x < 4096; x += 256) sS1[x] = scw1[x];
  for (int x = t; x < 2048; x += 256) {
    const int nn = x >> 7, c = x & 127;
    const int n = n0 + nn;
    snd[nn * 132 + c] = (n < N) ? nf[(size_t)n * 128 + c] : 0.f;
  }
  if (t < 64) {
    const int nn = t >> 2, c = t & 3;
    const int n = n0 + nn;
    snd[nn * 132 + 128 + c] = (n < N) ? na[(size_t)n * 4 + c] : 0.f;
  }
  __syncthreads();

  const float inv_sqrt32 = 0.17677669529663687f;
  const float sc_norm    = 0.08838834764831843f;  // 1/sqrt(32*4)

#pragma unroll
  for (int p = 0; p < 18; ++p) {
    const int idx = p * 256 + t;          // < 4608
    const int nn = idx / 288;
    const int o = idx - nn * 288;
    const int n = n0 + nn;
    if (n >= N) continue;
    const float* nd = snd + nn * 132;
    const float* nda = nd + 128;
    if (o < 32) {
      const int w = o;
      float acc = 0.f;
      for (int u = 0; u < 32; ++u) acc += nd[u] * sW0[u * 32 + w];
      y[(size_t)n * 128 + w] = acc * inv_sqrt32;
    } else if (o < 128) {
      const int q = o - 32, w = q / 3, i = q - w * 3;
      float acc = 0.f;
      for (int u = 0; u < 32; ++u) acc += nd[32 + u * 3 + i] * sW1[u * 32 + w];
      y[(size_t)n * 128 + 32 + w * 3 + i] = acc * inv_sqrt32;
    } else if (o < 192) {
      const int w = o - 128;
      float acc = 0.f;
      for (int k = 0; k < 128; ++k) acc += nd[k >> 2] * nda[k & 3] * sS0[k * 64 + w];
      sc[(size_t)n * 160 + w] = acc * sc_norm;
    } else {
      const int q = o - 192, w = q / 3, i = q - w * 3;
      float acc = 0.f;
      for (int k = 0; k < 128; ++k) acc += nd[32 + (k >> 2) * 3 + i] * nda[k & 3] * sS1[k * 32 + w];
      sc[(size_t)n * 160 + 64 + w * 3 + i] = acc * sc_norm;
    }
  }
}

// ---------------- CSR build (unchanged) ----------------
__global__ __launch_bounds__(256) void hist_kernel(const int* __restrict__ eidx,
                                                   int* __restrict__ counts, int E)
{
  const int e = blockIdx.x * 256 + threadIdx.x;
  if (e < E) atomicAdd(&counts[eidx[E + e]], 1);
}

__global__ __launch_bounds__(1024) void scan_kernel(const int* __restrict__ counts,
                                                    int* __restrict__ offsets,
                                                    int* __restrict__ cursor, int N)
{
  __shared__ int part[1024];
  const int t = threadIdx.x;
  const int per = (N + 1023) / 1024;
  const int base = t * per;
  int s = 0;
  for (int k = 0; k < per; ++k) { int idx = base + k; if (idx < N) s += counts[idx]; }
  part[t] = s;
  __syncthreads();
  for (int off = 1; off < 1024; off <<= 1) {
    int v = part[t];
    if (t >= off) v += part[t - off];
    __syncthreads();
    part[t] = v;
    __syncthreads();
  }
  int run = (t == 0) ? 0 : part[t - 1];
  for (int k = 0; k < per; ++k) {
    int idx = base + k;
    if (idx < N) { offsets[idx] = run; cursor[idx] = run; run += counts[idx]; }
  }
  if (t == 1023) offsets[N] = run;
}

__global__ __launch_bounds__(256) void scatter_kernel(const int* __restrict__ eidx,
                                                      int* __restrict__ cursor,
                                                      int* __restrict__ elist, int E)
{
  const int e = blockIdx.x * 256 + threadIdx.x;
  if (e >= E) return;
  const int dst = eidx[E + e];
  const int slot = atomicAdd(&cursor[dst], 1);
  elist[slot] = e;
}

// ---------------- Kernel 2: FUSED edge MLP; layer 3 via bf16 MFMA (R12) ----
__global__ __launch_bounds__(256) void edge_mlp_kernel(
    const float* __restrict__ eemb, const float* __restrict__ fw1,
    const float* __restrict__ fw2, const float* __restrict__ fw3,
    const int* __restrict__ elist, float* __restrict__ wbuf, int E)
{
  __shared__ __align__(16) float w1L[512];    // [k<64][r<8] transposed
  __shared__ __align__(16) float w2L[4096];   // B: w2 f32 ; C: w3 bf16 [n][k] swz
  __shared__ __align__(16) float hL[8192];    // A/B: h1 f32 [k][e] ; C: h2 bf16 [e][k] swz
  const int t = threadIdx.x;
  const int base = blockIdx.x * 128;

  for (int x = t; x < 512; x += 256)  w1L[x] = fw1[(x & 7) * 64 + (x >> 3)];
  for (int x = t; x < 4096; x += 256) w2L[x] = fw2[x];

  {
    const int e = t & 127, kg = t >> 7;
    const int slot0 = base + e;
    const int eid = (slot0 < E) ? elist[slot0] : 0;
    const float4 em0 = *(const float4*)(eemb + (size_t)eid * 8);
    const float4 em1 = *(const float4*)(eemb + (size_t)eid * 8 + 4);
    __syncthreads();

    const float inv_sqrt8 = 0.35355339059327373f;
#pragma unroll
    for (int kk = 0; kk < 32; ++kk) {
      const int k = kg * 32 + kk;
      const float4 wa = *(const float4*)(w1L + k * 8);
      const float4 wb = *(const float4*)(w1L + k * 8 + 4);
      const float a = em0.x * wa.x + em0.y * wa.y + em0.z * wa.z + em0.w * wa.w
                    + em1.x * wb.x + em1.y * wb.y + em1.z * wb.z + em1.w * wb.w;
      hL[k * 128 + e] = silu(a * inv_sqrt8);
    }
  }
  __syncthreads();

  const int og = t & 7, eg = t >> 3;
  const int e0 = eg * 4;

  float acc[4][8];
#pragma unroll
  for (int i = 0; i < 4; ++i)
#pragma unroll
    for (int j = 0; j < 8; ++j) acc[i][j] = 0.f;
  {
    const int o0 = og * 8;
    for (int k = 0; k < 64; ++k) {
      const float4 hv  = *(const float4*)(hL + k * 128 + e0);
      const float4 w0v = *(const float4*)(w2L + k * 64 + o0);
      const float4 w1v = *(const float4*)(w2L + k * 64 + o0 + 4);
      const float h[4] = {hv.x, hv.y, hv.z, hv.w};
      const float w[8] = {w0v.x, w0v.y, w0v.z, w0v.w, w1v.x, w1v.y, w1v.z, w1v.w};
#pragma unroll
      for (int i = 0; i < 4; ++i)
#pragma unroll
        for (int j = 0; j < 8; ++j) acc[i][j] += h[i] * w[j];
    }
  }
  __syncthreads();

#pragma unroll
  for (int i = 0; i < 4; ++i) {
    const int ee = e0 + i;
    short8v hv;
#pragma unroll
    for (int j = 0; j < 8; ++j)
      hv[j] = (short)f2bf(silu(acc[i][j] * 0.125f));
    *(short8v*)((char*)hL + ee * 128 + ((og ^ (ee & 7)) * 16)) = hv;
  }
  for (int x = t; x < 8192; x += 256) {
    const int k = x >> 7, c = x & 127;
    ((unsigned short*)((char*)w2L + c * 128 + (((k >> 3) ^ (c & 7)) * 16)))[k & 7] = f2bf(fw3[x]);
  }
  __syncthreads();

  {
    const int wv = t >> 6, l = t & 63;
    const int lrow = l & 15, lkg = l >> 4;
    f32x4 accd[2][8];
#pragma unroll
    for (int mt = 0; mt < 2; ++mt)
#pragma unroll
      for (int nt = 0; nt < 8; ++nt)
        accd[mt][nt] = (f32x4){0.f, 0.f, 0.f, 0.f};

#pragma unroll
    for (int step = 0; step < 2; ++step) {
      const int ea0 = wv * 32 + lrow;
      const int ea1 = wv * 32 + 16 + lrow;
      const short8v A0 = *(const short8v*)((const char*)hL + ea0 * 128 + (((step * 4 + lkg) ^ (ea0 & 7)) * 16));
      const short8v A1 = *(const short8v*)((const char*)hL + ea1 * 128 + (((step * 4 + lkg) ^ (ea1 & 7)) * 16));
#pragma unroll
      for (int nt = 0; nt < 8; ++nt) {
        const int n = nt * 16 + lrow;
        const short8v B = *(const short8v*)((const char*)w2L + n * 128 + (((step * 4 + lkg) ^ (n & 7)) * 16));
        accd[0][nt] = __builtin_amdgcn_mfma_f32_16x16x32_bf16(A0, B, accd[0][nt], 0, 0, 0);
        accd[1][nt] = __builtin_amdgcn_mfma_f32_16x16x32_bf16(A1, B, accd[1][nt], 0, 0, 0);
      }
    }
#pragma unroll
    for (int mt = 0; mt < 2; ++mt) {
#pragma unroll
      for (int r = 0; r < 4; ++r) {
        const int eo = wv * 32 + mt * 16 + lkg * 4 + r;
        const int slot = base + eo;
        if (slot < E) {
          float* wrow = wbuf + (size_t)slot * 128 + lrow;
#pragma unroll
          for (int nt = 0; nt < 8; ++nt)
            wrow[nt * 16] = accd[mt][nt][r] * 0.125f;
        }
      }
    }
  }
}

// ---------------- Kernel 3: wave-per-node gather + epilogue (R13) ----------
__global__ __launch_bounds__(256) void gather_out_kernel(
    const float* __restrict__ nf, const float* __restrict__ wbuf,
    const float* __restrict__ y, const float* __restrict__ sc,
    const float* __restrict__ l2w0, const float* __restrict__ l2w1,
    const int* __restrict__ offsets, const int* __restrict__ elist,
    const int* __restrict__ eidx, const float* __restrict__ eattr,
    const int* __restrict__ avgp, float* __restrict__ out, int N, int E)
{
  __shared__ float mW[4][264];    // per-wave m[256] (+pad)
  __shared__ float soW[4][160];   // per-wave so0[64] + so1[96]
  const int t = threadIdx.x;
  const int wv = t >> 6, l = t & 63;
  const int n = blockIdx.x * 4 + wv;
  const bool valid = (n < N);
  const int u = l & 31, half = l >> 5;

  const int beg = valid ? offsets[n] : 0;
  const int end = valid ? offsets[n + 1] : 0;

  float s0 = 0.f, s1 = 0.f;
  float v0x = 0.f, v0y = 0.f, v0z = 0.f;
  float v1x = 0.f, v1y = 0.f, v1z = 0.f;

  for (int s = beg + half; s < end; s += 2) {
    const int eid = elist[s];
    const int src = eidx[eid];
    const float4 ea = *(const float4*)(eattr + (size_t)eid * 4);
    const float* wr = wbuf + (size_t)s * 128;
    const float* yr = y + (size_t)src * 128;
    const float w00 = wr[u], w01 = wr[32 + u], w10 = wr[64 + u], w11 = wr[96 + u];
    const float g0  = yr[u];
    const float g1x = yr[32 + 3 * u], g1y = yr[33 + 3 * u], g1z = yr[34 + 3 * u];
    s0 += w00 * g0 * ea.x;
    const float t01 = w01 * g0;
    v0x += t01 * ea.y; v0y += t01 * ea.z; v0z += t01 * ea.w;
    const float wg = w10 * ea.x;
    v1x += wg * g1x; v1y += wg * g1y; v1z += wg * g1z;
    s1 += w11 * (g1x * ea.y + g1y * ea.z + g1z * ea.w);
  }
  s0 += __shfl_xor(s0, 32);  s1 += __shfl_xor(s1, 32);
  v0x += __shfl_xor(v0x, 32); v0y += __shfl_xor(v0y, 32); v0z += __shfl_xor(v0z, 32);
  v1x += __shfl_xor(v1x, 32); v1y += __shfl_xor(v1y, 32); v1z += __shfl_xor(v1z, 32);
  if (half == 0) {
    mW[wv][u]          = s0;
    mW[wv][32 + u]     = s1 * 0.5773502691896258f;
    mW[wv][64 + 3 * u] = v0x; mW[wv][65 + 3 * u] = v0y; mW[wv][66 + 3 * u] = v0z;
    mW[wv][160 + 3 * u] = v1x; mW[wv][161 + 3 * u] = v1y; mW[wv][162 + 3 * u] = v1z;
  }
  __syncthreads();

  const float scl = 0.125f * rsqrtf((float)(*avgp));
  const float* m = mW[wv];
  if (valid) {
    {
      float acc = 0.f;
      for (int uu = 0; uu < 64; ++uu) acc += m[uu] * l2w0[uu * 64 + l];
      soW[wv][l] = acc * scl + sc[(size_t)n * 160 + l];
    }
    {
      const int w = l / 3, i = l - 3 * w;
      float acc = 0.f;
      for (int uu = 0; uu < 64; ++uu) acc += m[64 + uu * 3 + i] * l2w1[uu * 32 + w];
      soW[wv][64 + l] = acc * scl + sc[(size_t)n * 160 + 64 + l];
    }
    if (l < 32) {
      const int q = 64 + l, w = q / 3, i = q - 3 * w;
      float acc = 0.f;
      for (int uu = 0; uu < 64; ++uu) acc += m[64 + uu * 3 + i] * l2w1[uu * 32 + w];
      soW[wv][64 + q] = acc * scl + sc[(size_t)n * 160 + 64 + q];
    }
  }
  __syncthreads();

  if (valid) {
#pragma unroll
    for (int p = 0; p < 2; ++p) {
      const int c = p * 64 + l;
      float val;
      if (c < 32) {
        val = silu(soW[wv][c]);
      } else {
        const int q = c - 32, w = q / 3, i = q - 3 * w;
        val = silu(soW[wv][32 + w]) * soW[wv][64 + w * 3 + i];
      }
      out[(size_t)n * 128 + c] = nf[(size_t)n * 128 + c] + val;
    }
  }
}

extern "C" void kernel_launch(void* const* d_in, const int* in_sizes, int n_in,
                              void* d_out, int out_size, void* d_ws, size_t ws_size,
                              hipStream_t stream)
{
  const float* nf    = (const float*)d_in[0];
  const float* na    = (const float*)d_in[1];
  const float* eattr = (const float*)d_in[2];
  const float* eemb  = (const float*)d_in[3];
  const float* l1w0  = (const float*)d_in[4];
  const float* l1w1  = (const float*)d_in[5];
  const float* fw1   = (const float*)d_in[6];
  const float* fw2   = (const float*)d_in[7];
  const float* fw3   = (const float*)d_in[8];
  const float* l2w0  = (const float*)d_in[9];
  const float* l2w1  = (const float*)d_in[10];
  const float* scw0  = (const float*)d_in[11];
  const float* scw1  = (const float*)d_in[12];
  const int*   eidx  = (const int*)d_in[13];
  const int*   avgp  = (const int*)d_in[14];

  const int N = in_sizes[0] / 128;
  const int E = in_sizes[2] / 4;

  // Same byte layout as R3-R13 (known to fit in ws_size).
  float* y       = (float*)d_ws;                    // N*128
  float* sc      = y + (size_t)N * 128;             // N*160
  float* wbuf    = sc + (size_t)N * 160;            // E*128 (slot-major, sorted by dst)
  int*   counts  = (int*)(wbuf + (size_t)E * 128);  // N
  int*   offsets = counts + N;                      // N+1
  int*   cursor  = offsets + N + 1;                 // N
  int*   elist   = cursor + N;                      // E (slot -> eid)

  hipMemsetAsync(counts, 0, (size_t)N * sizeof(int), stream);
  node_pre_kernel<<<(N + 15) / 16, 256, 0, stream>>>(nf, na, l1w0, l1w1, scw0, scw1, y, sc, N);
  hist_kernel<<<(E + 255) / 256, 256, 0, stream>>>(eidx, counts, E);
  scan_kernel<<<1, 1024, 0, stream>>>(counts, offsets, cursor, N);
  scatter_kernel<<<(E + 255) / 256, 256, 0, stream>>>(eidx, cursor, elist, E);
  edge_mlp_kernel<<<(E + 127) / 128, 256, 0, stream>>>(eemb, fw1, fw2, fw3, elist, wbuf, E);
  gather_out_kernel<<<(N + 3) / 4, 256, 0, stream>>>(nf, wbuf, y, sc, l2w0, l2w1,
                                                     offsets, elist, eidx, eattr, avgp,
                                                     (float*)d_out, N, E);
}

// Round 15
// 288.093 us; speedup vs baseline: 1.1930x; 1.1930x over previous
//
#include <hip/hip_runtime.h>
#include <math.h>

__device__ __forceinline__ float silu(float x) { return x / (1.0f + __expf(-x)); }

typedef __attribute__((ext_vector_type(8))) short short8v;  // 8 bf16 (4 VGPRs)
typedef __attribute__((ext_vector_type(4))) float f32x4;

__device__ __forceinline__ unsigned short f2bf(float x) {
  unsigned int u = __float_as_uint(x);
  return (unsigned short)((u + 0x8000u) >> 16);
}

// ---------------- Kernel 1: per-node precompute (R13 proven, 99us) ---------
__global__ __launch_bounds__(320) void node_pre_kernel(
    const float* __restrict__ nf, const float* __restrict__ na,
    const float* __restrict__ w0, const float* __restrict__ w1,
    const float* __restrict__ scw0, const float* __restrict__ scw1,
    float* __restrict__ y, float* __restrict__ sc)
{
  __shared__ float snf[128];
  __shared__ float sna[4];
  const int n = blockIdx.x;
  const int t = threadIdx.x;
  if (t < 128) snf[t] = nf[n * 128 + t];
  if (t >= 128 && t < 132) sna[t - 128] = na[n * 4 + (t - 128)];
  __syncthreads();
  const float inv_sqrt32 = 0.17677669529663687f;
  const float sc_norm    = 0.08838834764831843f;  // 1/sqrt(32*4)
  if (t < 32) {
    const int w = t;
    float acc = 0.f;
    for (int u = 0; u < 32; ++u) acc += snf[u] * w0[u * 32 + w];
    y[n * 128 + w] = acc * inv_sqrt32;
  } else if (t < 128) {
    const int q = t - 32, w = q / 3, i = q - w * 3;
    float acc = 0.f;
    for (int u = 0; u < 32; ++u) acc += snf[32 + u * 3 + i] * w1[u * 32 + w];
    y[n * 128 + 32 + w * 3 + i] = acc * inv_sqrt32;
  } else if (t < 192) {
    const int w = t - 128;
    float acc = 0.f;
    for (int k = 0; k < 128; ++k) acc += snf[k >> 2] * sna[k & 3] * scw0[k * 64 + w];
    sc[n * 160 + w] = acc * sc_norm;
  } else if (t < 288) {
    const int q = t - 192, w = q / 3, i = q - w * 3;
    float acc = 0.f;
    for (int k = 0; k < 128; ++k) acc += snf[32 + (k >> 2) * 3 + i] * sna[k & 3] * scw1[k * 32 + w];
    sc[n * 160 + 64 + w * 3 + i] = acc * sc_norm;
  }
}

// ---------------- CSR build (unchanged) ----------------
__global__ __launch_bounds__(256) void hist_kernel(const int* __restrict__ eidx,
                                                   int* __restrict__ counts, int E)
{
  const int e = blockIdx.x * 256 + threadIdx.x;
  if (e < E) atomicAdd(&counts[eidx[E + e]], 1);
}

__global__ __launch_bounds__(1024) void scan_kernel(const int* __restrict__ counts,
                                                    int* __restrict__ offsets,
                                                    int* __restrict__ cursor, int N)
{
  __shared__ int part[1024];
  const int t = threadIdx.x;
  const int per = (N + 1023) / 1024;
  const int base = t * per;
  int s = 0;
  for (int k = 0; k < per; ++k) { int idx = base + k; if (idx < N) s += counts[idx]; }
  part[t] = s;
  __syncthreads();
  for (int off = 1; off < 1024; off <<= 1) {
    int v = part[t];
    if (t >= off) v += part[t - off];
    __syncthreads();
    part[t] = v;
    __syncthreads();
  }
  int run = (t == 0) ? 0 : part[t - 1];
  for (int k = 0; k < per; ++k) {
    int idx = base + k;
    if (idx < N) { offsets[idx] = run; cursor[idx] = run; run += counts[idx]; }
  }
  if (t == 1023) offsets[N] = run;
}

__global__ __launch_bounds__(256) void scatter_kernel(const int* __restrict__ eidx,
                                                      int* __restrict__ cursor,
                                                      int* __restrict__ elist, int E)
{
  const int e = blockIdx.x * 256 + threadIdx.x;
  if (e >= E) return;
  const int dst = eidx[E + e];
  const int slot = atomicAdd(&cursor[dst], 1);
  elist[slot] = e;
}

// ---------------- Kernel 2: FUSED edge MLP; layers 2 AND 3 via bf16 MFMA ---
// reg1 (16KB): h1 bf16 [e=128][k=64] swz -> (reused) h2 bf16 [e][k=64] swz
// reg2 (32KB): w2T bf16 [o=64][k=64] swz -> (reused) w3 bf16 [n=128][k=64] swz
// chunk swizzle everywhere: 16B chunk index c at row r stored at (c ^ (r&7)).
__global__ __launch_bounds__(256) void edge_mlp_kernel(
    const float* __restrict__ eemb, const float* __restrict__ fw1,
    const float* __restrict__ fw2, const float* __restrict__ fw3,
    const int* __restrict__ elist, float* __restrict__ wbuf, int E)
{
  __shared__ __align__(16) float w1L[512];     // [k<64][r<8] transposed, f32
  __shared__ __align__(16) char reg1[16384];
  __shared__ __align__(16) char reg2[32768];
  const int t = threadIdx.x;
  const int base = blockIdx.x * 128;

  for (int x = t; x < 512; x += 256)  w1L[x] = fw1[(x & 7) * 64 + (x >> 3)];
  // stage w2T bf16 [o][k] swizzled
  for (int x = t; x < 4096; x += 256) {
    const int k = x >> 6, o = x & 63;
    *(unsigned short*)(reg2 + o * 128 + (((k >> 3) ^ (o & 7)) * 16) + (k & 7) * 2) = f2bf(fw2[x]);
  }

  // per-thread edge (2 threads per edge), emb in registers
  const int e = t & 127, kg = t >> 7;
  {
    const int slot0 = base + e;
    const int eid = (slot0 < E) ? elist[slot0] : 0;
    const float4 em0 = *(const float4*)(eemb + (size_t)eid * 8);
    const float4 em1 = *(const float4*)(eemb + (size_t)eid * 8 + 4);
    __syncthreads();

    // ---- phase A: h1 bf16 [e][k], 32 k per thread, 4 chunk stores ----
    const float inv_sqrt8 = 0.35355339059327373f;
#pragma unroll
    for (int c = 0; c < 4; ++c) {
      short8v hv;
#pragma unroll
      for (int j = 0; j < 8; ++j) {
        const int k = kg * 32 + c * 8 + j;
        const float4 wa = *(const float4*)(w1L + k * 8);
        const float4 wb = *(const float4*)(w1L + k * 8 + 4);
        const float a = em0.x * wa.x + em0.y * wa.y + em0.z * wa.z + em0.w * wa.w
                      + em1.x * wb.x + em1.y * wb.y + em1.z * wb.z + em1.w * wb.w;
        hv[j] = (short)f2bf(silu(a * inv_sqrt8));
      }
      const int cc = kg * 4 + c;
      *(short8v*)(reg1 + e * 128 + ((cc ^ (e & 7)) * 16)) = hv;
    }
  }
  __syncthreads();

  const int wv = t >> 6, l = t & 63;
  const int lrow = l & 15, lkg = l >> 4;

  // ---- phase B: h2 = silu(h1 @ w2 / 8) via MFMA (M=128,N=64,K=64) ----
  {
    f32x4 accB[2][4];
#pragma unroll
    for (int mt = 0; mt < 2; ++mt)
#pragma unroll
      for (int nt = 0; nt < 4; ++nt)
        accB[mt][nt] = (f32x4){0.f, 0.f, 0.f, 0.f};

#pragma unroll
    for (int step = 0; step < 2; ++step) {
#pragma unroll
      for (int mt = 0; mt < 2; ++mt) {
        const int ea = wv * 32 + mt * 16 + lrow;
        const short8v A = *(const short8v*)(reg1 + ea * 128 + (((step * 4 + lkg) ^ (ea & 7)) * 16));
#pragma unroll
        for (int nt = 0; nt < 4; ++nt) {
          const int o = nt * 16 + lrow;
          const short8v B = *(const short8v*)(reg2 + o * 128 + (((step * 4 + lkg) ^ (o & 7)) * 16));
          accB[mt][nt] = __builtin_amdgcn_mfma_f32_16x16x32_bf16(A, B, accB[mt][nt], 0, 0, 0);
        }
      }
    }
    __syncthreads();   // h1 reads + w2T reads complete; reg1/reg2 reusable

    // ---- D-store: h2 = silu(D/8) -> bf16 scalar stores into reg1 [e][o] ----
#pragma unroll
    for (int mt = 0; mt < 2; ++mt) {
#pragma unroll
      for (int r = 0; r < 4; ++r) {
        const int eo = wv * 32 + mt * 16 + lkg * 4 + r;
#pragma unroll
        for (int nt = 0; nt < 4; ++nt) {
          const int o = nt * 16 + lrow;
          const float val = silu(accB[mt][nt][r] * 0.125f);
          *(unsigned short*)(reg1 + eo * 128 + (((o >> 3) ^ (eo & 7)) * 16) + (o & 7) * 2) = f2bf(val);
        }
      }
    }
  }
  // ---- stage w3 bf16 [n=128][k=64] swizzled into reg2 ----
  for (int x = t; x < 8192; x += 256) {
    const int k = x >> 7, c = x & 127;
    *(unsigned short*)(reg2 + c * 128 + (((k >> 3) ^ (c & 7)) * 16) + (k & 7) * 2) = f2bf(fw3[x]);
  }
  __syncthreads();

  // ---- phase C: w = (h2 @ w3)/8 via MFMA (M=128,N=128,K=64), R12-proven ----
  {
    f32x4 accd[2][8];
#pragma unroll
    for (int mt = 0; mt < 2; ++mt)
#pragma unroll
      for (int nt = 0; nt < 8; ++nt)
        accd[mt][nt] = (f32x4){0.f, 0.f, 0.f, 0.f};

#pragma unroll
    for (int step = 0; step < 2; ++step) {
      const int ea0 = wv * 32 + lrow;
      const int ea1 = wv * 32 + 16 + lrow;
      const short8v A0 = *(const short8v*)(reg1 + ea0 * 128 + (((step * 4 + lkg) ^ (ea0 & 7)) * 16));
      const short8v A1 = *(const short8v*)(reg1 + ea1 * 128 + (((step * 4 + lkg) ^ (ea1 & 7)) * 16));
#pragma unroll
      for (int nt = 0; nt < 8; ++nt) {
        const int n = nt * 16 + lrow;
        const short8v B = *(const short8v*)(reg2 + n * 128 + (((step * 4 + lkg) ^ (n & 7)) * 16));
        accd[0][nt] = __builtin_amdgcn_mfma_f32_16x16x32_bf16(A0, B, accd[0][nt], 0, 0, 0);
        accd[1][nt] = __builtin_amdgcn_mfma_f32_16x16x32_bf16(A1, B, accd[1][nt], 0, 0, 0);
      }
    }
#pragma unroll
    for (int mt = 0; mt < 2; ++mt) {
#pragma unroll
      for (int r = 0; r < 4; ++r) {
        const int eo = wv * 32 + mt * 16 + lkg * 4 + r;
        const int slot = base + eo;
        if (slot < E) {
          float* wrow = wbuf + (size_t)slot * 128 + lrow;
#pragma unroll
          for (int nt = 0; nt < 8; ++nt)
            wrow[nt * 16] = accd[mt][nt][r] * 0.125f;
        }
      }
    }
  }
}

// ---------------- Kernel 3: wave-per-node gather + epilogue (R13) ----------
__global__ __launch_bounds__(256) void gather_out_kernel(
    const float* __restrict__ nf, const float* __restrict__ wbuf,
    const float* __restrict__ y, const float* __restrict__ sc,
    const float* __restrict__ l2w0, const float* __restrict__ l2w1,
    const int* __restrict__ offsets, const int* __restrict__ elist,
    const int* __restrict__ eidx, const float* __restrict__ eattr,
    const int* __restrict__ avgp, float* __restrict__ out, int N, int E)
{
  __shared__ float mW[4][264];    // per-wave m[256] (+pad)
  __shared__ float soW[4][160];   // per-wave so0[64] + so1[96]
  const int t = threadIdx.x;
  const int wv = t >> 6, l = t & 63;
  const int n = blockIdx.x * 4 + wv;
  const bool valid = (n < N);
  const int u = l & 31, half = l >> 5;

  const int beg = valid ? offsets[n] : 0;
  const int end = valid ? offsets[n + 1] : 0;

  float s0 = 0.f, s1 = 0.f;
  float v0x = 0.f, v0y = 0.f, v0z = 0.f;
  float v1x = 0.f, v1y = 0.f, v1z = 0.f;

  for (int s = beg + half; s < end; s += 2) {
    const int eid = elist[s];
    const int src = eidx[eid];
    const float4 ea = *(const float4*)(eattr + (size_t)eid * 4);
    const float* wr = wbuf + (size_t)s * 128;
    const float* yr = y + (size_t)src * 128;
    const float w00 = wr[u], w01 = wr[32 + u], w10 = wr[64 + u], w11 = wr[96 + u];
    const float g0  = yr[u];
    const float g1x = yr[32 + 3 * u], g1y = yr[33 + 3 * u], g1z = yr[34 + 3 * u];
    s0 += w00 * g0 * ea.x;
    const float t01 = w01 * g0;
    v0x += t01 * ea.y; v0y += t01 * ea.z; v0z += t01 * ea.w;
    const float wg = w10 * ea.x;
    v1x += wg * g1x; v1y += wg * g1y; v1z += wg * g1z;
    s1 += w11 * (g1x * ea.y + g1y * ea.z + g1z * ea.w);
  }
  s0 += __shfl_xor(s0, 32);  s1 += __shfl_xor(s1, 32);
  v0x += __shfl_xor(v0x, 32); v0y += __shfl_xor(v0y, 32); v0z += __shfl_xor(v0z, 32);
  v1x += __shfl_xor(v1x, 32); v1y += __shfl_xor(v1y, 32); v1z += __shfl_xor(v1z, 32);
  if (half == 0) {
    mW[wv][u]          = s0;
    mW[wv][32 + u]     = s1 * 0.5773502691896258f;
    mW[wv][64 + 3 * u] = v0x; mW[wv][65 + 3 * u] = v0y; mW[wv][66 + 3 * u] = v0z;
    mW[wv][160 + 3 * u] = v1x; mW[wv][161 + 3 * u] = v1y; mW[wv][162 + 3 * u] = v1z;
  }
  __syncthreads();

  const float scl = 0.125f * rsqrtf((float)(*avgp));
  const float* m = mW[wv];
  if (valid) {
    {
      float acc = 0.f;
      for (int uu = 0; uu < 64; ++uu) acc += m[uu] * l2w0[uu * 64 + l];
      soW[wv][l] = acc * scl + sc[(size_t)n * 160 + l];
    }
    {
      const int w = l / 3, i = l - 3 * w;
      float acc = 0.f;
      for (int uu = 0; uu < 64; ++uu) acc += m[64 + uu * 3 + i] * l2w1[uu * 32 + w];
      soW[wv][64 + l] = acc * scl + sc[(size_t)n * 160 + 64 + l];
    }
    if (l < 32) {
      const int q = 64 + l, w = q / 3, i = q - 3 * w;
      float acc = 0.f;
      for (int uu = 0; uu < 64; ++uu) acc += m[64 + uu * 3 + i] * l2w1[uu * 32 + w];
      soW[wv][64 + q] = acc * scl + sc[(size_t)n * 160 + 64 + q];
    }
  }
  __syncthreads();

  if (valid) {
#pragma unroll
    for (int p = 0; p < 2; ++p) {
      const int c = p * 64 + l;
      float val;
      if (c < 32) {
        val = silu(soW[wv][c]);
      } else {
        const int q = c - 32, w = q / 3, i = q - 3 * w;
        val = silu(soW[wv][32 + w]) * soW[wv][64 + w * 3 + i];
      }
      out[(size_t)n * 128 + c] = nf[(size_t)n * 128 + c] + val;
    }
  }
}

extern "C" void kernel_launch(void* const* d_in, const int* in_sizes, int n_in,
                              void* d_out, int out_size, void* d_ws, size_t ws_size,
                              hipStream_t stream)
{
  const float* nf    = (const float*)d_in[0];
  const float* na    = (const float*)d_in[1];
  const float* eattr = (const float*)d_in[2];
  const float* eemb  = (const float*)d_in[3];
  const float* l1w0  = (const float*)d_in[4];
  const float* l1w1  = (const float*)d_in[5];
  const float* fw1   = (const float*)d_in[6];
  const float* fw2   = (const float*)d_in[7];
  const float* fw3   = (const float*)d_in[8];
  const float* l2w0  = (const float*)d_in[9];
  const float* l2w1  = (const float*)d_in[10];
  const float* scw0  = (const float*)d_in[11];
  const float* scw1  = (const float*)d_in[12];
  const int*   eidx  = (const int*)d_in[13];
  const int*   avgp  = (const int*)d_in[14];

  const int N = in_sizes[0] / 128;
  const int E = in_sizes[2] / 4;

  // Same byte layout as R3-R14 (known to fit in ws_size).
  float* y       = (float*)d_ws;                    // N*128
  float* sc      = y + (size_t)N * 128;             // N*160
  float* wbuf    = sc + (size_t)N * 160;            // E*128 (slot-major, sorted by dst)
  int*   counts  = (int*)(wbuf + (size_t)E * 128);  // N
  int*   offsets = counts + N;                      // N+1
  int*   cursor  = offsets + N + 1;                 // N
  int*   elist   = cursor + N;                      // E (slot -> eid)

  hipMemsetAsync(counts, 0, (size_t)N * sizeof(int), stream);
  node_pre_kernel<<<N, 320, 0, stream>>>(nf, na, l1w0, l1w1, scw0, scw1, y, sc);
  hist_kernel<<<(E + 255) / 256, 256, 0, stream>>>(eidx, counts, E);
  scan_kernel<<<1, 1024, 0, stream>>>(counts, offsets, cursor, N);
  scatter_kernel<<<(E + 255) / 256, 256, 0, stream>>>(eidx, cursor, elist, E);
  edge_mlp_kernel<<<(E + 127) / 128, 256, 0, stream>>>(eemb, fw1, fw2, fw3, elist, wbuf, E);
  gather_out_kernel<<<(N + 3) / 4, 256, 0, stream>>>(nf, wbuf, y, sc, l2w0, l2w1,
                                                     offsets, elist, eidx, eattr, avgp,
                                                     (float*)d_out, N, E);
}

// Round 16
// 223.321 us; speedup vs baseline: 1.5390x; 1.2900x over previous
//
#include <hip/hip_runtime.h>
#include <math.h>

__device__ __forceinline__ float silu(float x) { return x / (1.0f + __expf(-x)); }

typedef __attribute__((ext_vector_type(8))) short short8v;  // 8 bf16 (4 VGPRs)
typedef __attribute__((ext_vector_type(4))) float f32x4;

__device__ __forceinline__ unsigned short f2bf(float x) {
  unsigned int u = __float_as_uint(x);
  return (unsigned short)((u + 0x8000u) >> 16);
}

// ---------------- Kernel 1: node precompute via bf16 MFMA, 32 nodes/block --
// LDS: nfL f32 [32][132] (nf + na), aB bf16 A-tile [32][64k swz], wB = all
// weights bf16 [row][64k swz] (w0T, w1T, scw0T lo/hi, scw1T lo/hi).
// A/B/D fragment mappings identical to edge_mlp (proven R12/R15).
__global__ __launch_bounds__(256) void node_pre_kernel(
    const float* __restrict__ nf, const float* __restrict__ na,
    const float* __restrict__ w0, const float* __restrict__ w1,
    const float* __restrict__ scw0, const float* __restrict__ scw1,
    float* __restrict__ y, float* __restrict__ sc, int N)
{
  __shared__ float nfL[32][132];
  __shared__ __align__(16) char aB[4096];
  __shared__ __align__(16) char wB[32768];
  const int t = threadIdx.x;
  const int n0 = blockIdx.x * 32;
  const int wv = t >> 6, l = t & 63;
  const int lrow = l & 15, lkg = l >> 4;
  const int ann = t >> 3, ac = t & 7;   // A-build: thread -> (node, chunk)
  const float inv_sqrt32 = 0.17677669529663687f;
  const float sc_norm    = 0.08838834764831843f;  // 1/sqrt(32*4)

  // ---- stage nfL (coalesced) ----
  for (int x4 = t; x4 < 1024; x4 += 256) {
    const int nn = x4 >> 5, c4 = x4 & 31;
    const int n = n0 + nn;
    float4 v = make_float4(0.f, 0.f, 0.f, 0.f);
    if (n < N) v = *(const float4*)(nf + (size_t)n * 128 + c4 * 4);
    *(float4*)&nfL[nn][c4 * 4] = v;
  }
  if (t < 128) {
    const int nn = t >> 2, c = t & 3;
    const int n = n0 + nn;
    nfL[nn][128 + c] = (n < N) ? na[(size_t)n * 4 + c] : 0.f;
  }
  // ---- stage weights bf16 transposed [row][k] chunk-swizzled ----
  for (int x = t; x < 1024; x += 256) {          // w0T @0: row=w, k=u
    const int u = x >> 5, w = x & 31;
    *(unsigned short*)(wB + 0 + w * 128 + (((u >> 3) ^ (w & 7)) * 16) + (u & 7) * 2) = f2bf(w0[x]);
  }
  for (int x = t; x < 1024; x += 256) {          // w1T @4K
    const int u = x >> 5, w = x & 31;
    *(unsigned short*)(wB + 4096 + w * 128 + (((u >> 3) ^ (w & 7)) * 16) + (u & 7) * 2) = f2bf(w1[x]);
  }
  for (int x = t; x < 8192; x += 256) {          // scw0T lo@8K hi@16K: row=c, k
    const int k = x >> 6, c = x & 63;
    const int half = k >> 6, kk = k & 63;
    *(unsigned short*)(wB + 8192 + half * 8192 + c * 128 + (((kk >> 3) ^ (c & 7)) * 16) + (kk & 7) * 2) = f2bf(scw0[x]);
  }
  for (int x = t; x < 4096; x += 256) {          // scw1T lo@24K hi@28K
    const int k = x >> 5, c = x & 31;
    const int half = k >> 6, kk = k & 63;
    *(unsigned short*)(wB + 24576 + half * 4096 + c * 128 + (((kk >> 3) ^ (c & 7)) * 16) + (kk & 7) * 2) = f2bf(scw1[x]);
  }
  __syncthreads();

  // ================= lin1 y0: A = x0 (K=32, single MFMA step) =============
  if (ac < 4) {
    short8v hv;
#pragma unroll
    for (int j = 0; j < 8; ++j) hv[j] = (short)f2bf(nfL[ann][ac * 8 + j]);
    *(short8v*)(aB + ann * 128 + ((ac ^ (ann & 7)) * 16));
    *(short8v*)(aB + ann * 128 + ((ac ^ (ann & 7)) * 16)) = hv;
  }
  __syncthreads();
  {
    const int mt = wv >> 1, nt = wv & 1;
    const int ar = mt * 16 + lrow, br = nt * 16 + lrow;
    const short8v A = *(const short8v*)(aB + ar * 128 + ((lkg ^ (ar & 7)) * 16));
    const short8v B = *(const short8v*)(wB + 0 + br * 128 + ((lkg ^ (br & 7)) * 16));
    f32x4 acc = (f32x4){0.f, 0.f, 0.f, 0.f};
    acc = __builtin_amdgcn_mfma_f32_16x16x32_bf16(A, B, acc, 0, 0, 0);
#pragma unroll
    for (int r = 0; r < 4; ++r) {
      const int nn = mt * 16 + lkg * 4 + r;
      const int n = n0 + nn;
      if (n < N) y[(size_t)n * 128 + nt * 16 + lrow] = acc[r] * inv_sqrt32;
    }
  }
  __syncthreads();

  // ================= lin1 y1, components i=0..2 (K=32 each) ===============
  for (int i = 0; i < 3; ++i) {
    if (ac < 4) {
      short8v hv;
#pragma unroll
      for (int j = 0; j < 8; ++j)
        hv[j] = (short)f2bf(nfL[ann][32 + (ac * 8 + j) * 3 + i]);
      *(short8v*)(aB + ann * 128 + ((ac ^ (ann & 7)) * 16)) = hv;
    }
    __syncthreads();
    {
      const int mt = wv >> 1, nt = wv & 1;
      const int ar = mt * 16 + lrow, br = nt * 16 + lrow;
      const short8v A = *(const short8v*)(aB + ar * 128 + ((lkg ^ (ar & 7)) * 16));
      const short8v B = *(const short8v*)(wB + 4096 + br * 128 + ((lkg ^ (br & 7)) * 16));
      f32x4 acc = (f32x4){0.f, 0.f, 0.f, 0.f};
      acc = __builtin_amdgcn_mfma_f32_16x16x32_bf16(A, B, acc, 0, 0, 0);
#pragma unroll
      for (int r = 0; r < 4; ++r) {
        const int nn = mt * 16 + lkg * 4 + r;
        const int n = n0 + nn;
        if (n < N) y[(size_t)n * 128 + 32 + (nt * 16 + lrow) * 3 + i] = acc[r] * inv_sqrt32;
      }
    }
    __syncthreads();
  }

  // ================= sc0: B[n,k]=x0[k>>2]*na[k&3], K=128, N=64 ============
  {
    f32x4 accS[2] = {(f32x4){0.f,0.f,0.f,0.f}, (f32x4){0.f,0.f,0.f,0.f}};
    const int mt = wv & 1, ntb = (wv >> 1) * 2;
#pragma unroll
    for (int half = 0; half < 2; ++half) {
      {  // build A for this half: k = half*64 + ac*8 + j
        short8v hv;
#pragma unroll
        for (int j = 0; j < 8; ++j) {
          const int k = half * 64 + ac * 8 + j;
          hv[j] = (short)f2bf(nfL[ann][k >> 2] * nfL[ann][128 + (k & 3)]);
        }
        *(short8v*)(aB + ann * 128 + ((ac ^ (ann & 7)) * 16)) = hv;
      }
      __syncthreads();
#pragma unroll
      for (int step = 0; step < 2; ++step) {
        const int ar = mt * 16 + lrow;
        const short8v A = *(const short8v*)(aB + ar * 128 + (((step * 4 + lkg) ^ (ar & 7)) * 16));
#pragma unroll
        for (int q = 0; q < 2; ++q) {
          const int br = (ntb + q) * 16 + lrow;
          const short8v B = *(const short8v*)(wB + 8192 + half * 8192 + br * 128 + (((step * 4 + lkg) ^ (br & 7)) * 16));
          accS[q] = __builtin_amdgcn_mfma_f32_16x16x32_bf16(A, B, accS[q], 0, 0, 0);
        }
      }
      __syncthreads();
    }
#pragma unroll
    for (int q = 0; q < 2; ++q) {
#pragma unroll
      for (int r = 0; r < 4; ++r) {
        const int nn = mt * 16 + lkg * 4 + r;
        const int n = n0 + nn;
        if (n < N) sc[(size_t)n * 160 + (ntb + q) * 16 + lrow] = accS[q][r] * sc_norm;
      }
    }
  }
  // (no barrier needed before next build: sc0's last consumer of aB was
  //  before its trailing __syncthreads inside the half-loop)

  // ================= sc1, components i=0..2: K=128, N=32 ==================
  for (int i = 0; i < 3; ++i) {
    f32x4 acc = (f32x4){0.f, 0.f, 0.f, 0.f};
    const int mt = wv >> 1, nt = wv & 1;
#pragma unroll
    for (int half = 0; half < 2; ++half) {
      {
        short8v hv;
#pragma unroll
        for (int j = 0; j < 8; ++j) {
          const int k = half * 64 + ac * 8 + j;
          hv[j] = (short)f2bf(nfL[ann][32 + (k >> 2) * 3 + i] * nfL[ann][128 + (k & 3)]);
        }
        *(short8v*)(aB + ann * 128 + ((ac ^ (ann & 7)) * 16)) = hv;
      }
      __syncthreads();
#pragma unroll
      for (int step = 0; step < 2; ++step) {
        const int ar = mt * 16 + lrow;
        const short8v A = *(const short8v*)(aB + ar * 128 + (((step * 4 + lkg) ^ (ar & 7)) * 16));
        const int br = nt * 16 + lrow;
        const short8v B = *(const short8v*)(wB + 24576 + half * 4096 + br * 128 + (((step * 4 + lkg) ^ (br & 7)) * 16));
        acc = __builtin_amdgcn_mfma_f32_16x16x32_bf16(A, B, acc, 0, 0, 0);
      }
      __syncthreads();
    }
#pragma unroll
    for (int r = 0; r < 4; ++r) {
      const int nn = mt * 16 + lkg * 4 + r;
      const int n = n0 + nn;
      if (n < N) sc[(size_t)n * 160 + 64 + (nt * 16 + lrow) * 3 + i] = acc[r] * sc_norm;
    }
  }
}

// ---------------- CSR build (unchanged) ----------------
__global__ __launch_bounds__(256) void hist_kernel(const int* __restrict__ eidx,
                                                   int* __restrict__ counts, int E)
{
  const int e = blockIdx.x * 256 + threadIdx.x;
  if (e < E) atomicAdd(&counts[eidx[E + e]], 1);
}

__global__ __launch_bounds__(1024) void scan_kernel(const int* __restrict__ counts,
                                                    int* __restrict__ offsets,
                                                    int* __restrict__ cursor, int N)
{
  __shared__ int part[1024];
  const int t = threadIdx.x;
  const int per = (N + 1023) / 1024;
  const int base = t * per;
  int s = 0;
  for (int k = 0; k < per; ++k) { int idx = base + k; if (idx < N) s += counts[idx]; }
  part[t] = s;
  __syncthreads();
  for (int off = 1; off < 1024; off <<= 1) {
    int v = part[t];
    if (t >= off) v += part[t - off];
    __syncthreads();
    part[t] = v;
    __syncthreads();
  }
  int run = (t == 0) ? 0 : part[t - 1];
  for (int k = 0; k < per; ++k) {
    int idx = base + k;
    if (idx < N) { offsets[idx] = run; cursor[idx] = run; run += counts[idx]; }
  }
  if (t == 1023) offsets[N] = run;
}

__global__ __launch_bounds__(256) void scatter_kernel(const int* __restrict__ eidx,
                                                      int* __restrict__ cursor,
                                                      int* __restrict__ elist, int E)
{
  const int e = blockIdx.x * 256 + threadIdx.x;
  if (e >= E) return;
  const int dst = eidx[E + e];
  const int slot = atomicAdd(&cursor[dst], 1);
  elist[slot] = e;
}

// ---------------- Kernel 2: FUSED edge MLP; layers 2+3 via bf16 MFMA (R15) -
__global__ __launch_bounds__(256) void edge_mlp_kernel(
    const float* __restrict__ eemb, const float* __restrict__ fw1,
    const float* __restrict__ fw2, const float* __restrict__ fw3,
    const int* __restrict__ elist, float* __restrict__ wbuf, int E)
{
  __shared__ __align__(16) float w1L[512];     // [k<64][r<8] transposed, f32
  __shared__ __align__(16) char reg1[16384];
  __shared__ __align__(16) char reg2[32768];
  const int t = threadIdx.x;
  const int base = blockIdx.x * 128;

  for (int x = t; x < 512; x += 256)  w1L[x] = fw1[(x & 7) * 64 + (x >> 3)];
  for (int x = t; x < 4096; x += 256) {
    const int k = x >> 6, o = x & 63;
    *(unsigned short*)(reg2 + o * 128 + (((k >> 3) ^ (o & 7)) * 16) + (k & 7) * 2) = f2bf(fw2[x]);
  }

  const int e = t & 127, kg = t >> 7;
  {
    const int slot0 = base + e;
    const int eid = (slot0 < E) ? elist[slot0] : 0;
    const float4 em0 = *(const float4*)(eemb + (size_t)eid * 8);
    const float4 em1 = *(const float4*)(eemb + (size_t)eid * 8 + 4);
    __syncthreads();

    const float inv_sqrt8 = 0.35355339059327373f;
#pragma unroll
    for (int c = 0; c < 4; ++c) {
      short8v hv;
#pragma unroll
      for (int j = 0; j < 8; ++j) {
        const int k = kg * 32 + c * 8 + j;
        const float4 wa = *(const float4*)(w1L + k * 8);
        const float4 wb = *(const float4*)(w1L + k * 8 + 4);
        const float a = em0.x * wa.x + em0.y * wa.y + em0.z * wa.z + em0.w * wa.w
                      + em1.x * wb.x + em1.y * wb.y + em1.z * wb.z + em1.w * wb.w;
        hv[j] = (short)f2bf(silu(a * inv_sqrt8));
      }
      const int cc = kg * 4 + c;
      *(short8v*)(reg1 + e * 128 + ((cc ^ (e & 7)) * 16)) = hv;
    }
  }
  __syncthreads();

  const int wv = t >> 6, l = t & 63;
  const int lrow = l & 15, lkg = l >> 4;

  {
    f32x4 accB[2][4];
#pragma unroll
    for (int mt = 0; mt < 2; ++mt)
#pragma unroll
      for (int nt = 0; nt < 4; ++nt)
        accB[mt][nt] = (f32x4){0.f, 0.f, 0.f, 0.f};

#pragma unroll
    for (int step = 0; step < 2; ++step) {
#pragma unroll
      for (int mt = 0; mt < 2; ++mt) {
        const int ea = wv * 32 + mt * 16 + lrow;
        const short8v A = *(const short8v*)(reg1 + ea * 128 + (((step * 4 + lkg) ^ (ea & 7)) * 16));
#pragma unroll
        for (int nt = 0; nt < 4; ++nt) {
          const int o = nt * 16 + lrow;
          const short8v B = *(const short8v*)(reg2 + o * 128 + (((step * 4 + lkg) ^ (o & 7)) * 16));
          accB[mt][nt] = __builtin_amdgcn_mfma_f32_16x16x32_bf16(A, B, accB[mt][nt], 0, 0, 0);
        }
      }
    }
    __syncthreads();

#pragma unroll
    for (int mt = 0; mt < 2; ++mt) {
#pragma unroll
      for (int r = 0; r < 4; ++r) {
        const int eo = wv * 32 + mt * 16 + lkg * 4 + r;
#pragma unroll
        for (int nt = 0; nt < 4; ++nt) {
          const int o = nt * 16 + lrow;
          const float val = silu(accB[mt][nt][r] * 0.125f);
          *(unsigned short*)(reg1 + eo * 128 + (((o >> 3) ^ (eo & 7)) * 16) + (o & 7) * 2) = f2bf(val);
        }
      }
    }
  }
  for (int x = t; x < 8192; x += 256) {
    const int k = x >> 7, c = x & 127;
    *(unsigned short*)(reg2 + c * 128 + (((k >> 3) ^ (c & 7)) * 16) + (k & 7) * 2) = f2bf(fw3[x]);
  }
  __syncthreads();

  {
    f32x4 accd[2][8];
#pragma unroll
    for (int mt = 0; mt < 2; ++mt)
#pragma unroll
      for (int nt = 0; nt < 8; ++nt)
        accd[mt][nt] = (f32x4){0.f, 0.f, 0.f, 0.f};

#pragma unroll
    for (int step = 0; step < 2; ++step) {
      const int ea0 = wv * 32 + lrow;
      const int ea1 = wv * 32 + 16 + lrow;
      const short8v A0 = *(const short8v*)(reg1 + ea0 * 128 + (((step * 4 + lkg) ^ (ea0 & 7)) * 16));
      const short8v A1 = *(const short8v*)(reg1 + ea1 * 128 + (((step * 4 + lkg) ^ (ea1 & 7)) * 16));
#pragma unroll
      for (int nt = 0; nt < 8; ++nt) {
        const int n = nt * 16 + lrow;
        const short8v B = *(const short8v*)(reg2 + n * 128 + (((step * 4 + lkg) ^ (n & 7)) * 16));
        accd[0][nt] = __builtin_amdgcn_mfma_f32_16x16x32_bf16(A0, B, accd[0][nt], 0, 0, 0);
        accd[1][nt] = __builtin_amdgcn_mfma_f32_16x16x32_bf16(A1, B, accd[1][nt], 0, 0, 0);
      }
    }
#pragma unroll
    for (int mt = 0; mt < 2; ++mt) {
#pragma unroll
      for (int r = 0; r < 4; ++r) {
        const int eo = wv * 32 + mt * 16 + lkg * 4 + r;
        const int slot = base + eo;
        if (slot < E) {
          float* wrow = wbuf + (size_t)slot * 128 + lrow;
#pragma unroll
          for (int nt = 0; nt < 8; ++nt)
            wrow[nt * 16] = accd[mt][nt][r] * 0.125f;
        }
      }
    }
  }
}

// ---------------- Kernel 3: wave-per-node gather + epilogue (R13) ----------
__global__ __launch_bounds__(256) void gather_out_kernel(
    const float* __restrict__ nf, const float* __restrict__ wbuf,
    const float* __restrict__ y, const float* __restrict__ sc,
    const float* __restrict__ l2w0, const float* __restrict__ l2w1,
    const int* __restrict__ offsets, const int* __restrict__ elist,
    const int* __restrict__ eidx, const float* __restrict__ eattr,
    const int* __restrict__ avgp, float* __restrict__ out, int N, int E)
{
  __shared__ float mW[4][264];    // per-wave m[256] (+pad)
  __shared__ float soW[4][160];   // per-wave so0[64] + so1[96]
  const int t = threadIdx.x;
  const int wv = t >> 6, l = t & 63;
  const int n = blockIdx.x * 4 + wv;
  const bool valid = (n < N);
  const int u = l & 31, half = l >> 5;

  const int beg = valid ? offsets[n] : 0;
  const int end = valid ? offsets[n + 1] : 0;

  float s0 = 0.f, s1 = 0.f;
  float v0x = 0.f, v0y = 0.f, v0z = 0.f;
  float v1x = 0.f, v1y = 0.f, v1z = 0.f;

  for (int s = beg + half; s < end; s += 2) {
    const int eid = elist[s];
    const int src = eidx[eid];
    const float4 ea = *(const float4*)(eattr + (size_t)eid * 4);
    const float* wr = wbuf + (size_t)s * 128;
    const float* yr = y + (size_t)src * 128;
    const float w00 = wr[u], w01 = wr[32 + u], w10 = wr[64 + u], w11 = wr[96 + u];
    const float g0  = yr[u];
    const float g1x = yr[32 + 3 * u], g1y = yr[33 + 3 * u], g1z = yr[34 + 3 * u];
    s0 += w00 * g0 * ea.x;
    const float t01 = w01 * g0;
    v0x += t01 * ea.y; v0y += t01 * ea.z; v0z += t01 * ea.w;
    const float wg = w10 * ea.x;
    v1x += wg * g1x; v1y += wg * g1y; v1z += wg * g1z;
    s1 += w11 * (g1x * ea.y + g1y * ea.z + g1z * ea.w);
  }
  s0 += __shfl_xor(s0, 32);  s1 += __shfl_xor(s1, 32);
  v0x += __shfl_xor(v0x, 32); v0y += __shfl_xor(v0y, 32); v0z += __shfl_xor(v0z, 32);
  v1x += __shfl_xor(v1x, 32); v1y += __shfl_xor(v1y, 32); v1z += __shfl_xor(v1z, 32);
  if (half == 0) {
    mW[wv][u]          = s0;
    mW[wv][32 + u]     = s1 * 0.5773502691896258f;
    mW[wv][64 + 3 * u] = v0x; mW[wv][65 + 3 * u] = v0y; mW[wv][66 + 3 * u] = v0z;
    mW[wv][160 + 3 * u] = v1x; mW[wv][161 + 3 * u] = v1y; mW[wv][162 + 3 * u] = v1z;
  }
  __syncthreads();

  const float scl = 0.125f * rsqrtf((float)(*avgp));
  const float* m = mW[wv];
  if (valid) {
    {
      float acc = 0.f;
      for (int uu = 0; uu < 64; ++uu) acc += m[uu] * l2w0[uu * 64 + l];
      soW[wv][l] = acc * scl + sc[(size_t)n * 160 + l];
    }
    {
      const int w = l / 3, i = l - 3 * w;
      float acc = 0.f;
      for (int uu = 0; uu < 64; ++uu) acc += m[64 + uu * 3 + i] * l2w1[uu * 32 + w];
      soW[wv][64 + l] = acc * scl + sc[(size_t)n * 160 + 64 + l];
    }
    if (l < 32) {
      const int q = 64 + l, w = q / 3, i = q - 3 * w;
      float acc = 0.f;
      for (int uu = 0; uu < 64; ++uu) acc += m[64 + uu * 3 + i] * l2w1[uu * 32 + w];
      soW[wv][64 + q] = acc * scl + sc[(size_t)n * 160 + 64 + q];
    }
  }
  __syncthreads();

  if (valid) {
#pragma unroll
    for (int p = 0; p < 2; ++p) {
      const int c = p * 64 + l;
      float val;
      if (c < 32) {
        val = silu(soW[wv][c]);
      } else {
        const int q = c - 32, w = q / 3, i = q - 3 * w;
        val = silu(soW[wv][32 + w]) * soW[wv][64 + w * 3 + i];
      }
      out[(size_t)n * 128 + c] = nf[(size_t)n * 128 + c] + val;
    }
  }
}

extern "C" void kernel_launch(void* const* d_in, const int* in_sizes, int n_in,
                              void* d_out, int out_size, void* d_ws, size_t ws_size,
                              hipStream_t stream)
{
  const float* nf    = (const float*)d_in[0];
  const float* na    = (const float*)d_in[1];
  const float* eattr = (const float*)d_in[2];
  const float* eemb  = (const float*)d_in[3];
  const float* l1w0  = (const float*)d_in[4];
  const float* l1w1  = (const float*)d_in[5];
  const float* fw1   = (const float*)d_in[6];
  const float* fw2   = (const float*)d_in[7];
  const float* fw3   = (const float*)d_in[8];
  const float* l2w0  = (const float*)d_in[9];
  const float* l2w1  = (const float*)d_in[10];
  const float* scw0  = (const float*)d_in[11];
  const float* scw1  = (const float*)d_in[12];
  const int*   eidx  = (const int*)d_in[13];
  const int*   avgp  = (const int*)d_in[14];

  const int N = in_sizes[0] / 128;
  const int E = in_sizes[2] / 4;

  // Same byte layout as R3-R15 (known to fit in ws_size).
  float* y       = (float*)d_ws;                    // N*128
  float* sc      = y + (size_t)N * 128;             // N*160
  float* wbuf    = sc + (size_t)N * 160;            // E*128 (slot-major, sorted by dst)
  int*   counts  = (int*)(wbuf + (size_t)E * 128);  // N
  int*   offsets = counts + N;                      // N+1
  int*   cursor  = offsets + N + 1;                 // N
  int*   elist   = cursor + N;                      // E (slot -> eid)

  hipMemsetAsync(counts, 0, (size_t)N * sizeof(int), stream);
  node_pre_kernel<<<(N + 31) / 32, 256, 0, stream>>>(nf, na, l1w0, l1w1, scw0, scw1, y, sc, N);
  hist_kernel<<<(E + 255) / 256, 256, 0, stream>>>(eidx, counts, E);
  scan_kernel<<<1, 1024, 0, stream>>>(counts, offsets, cursor, N);
  scatter_kernel<<<(E + 255) / 256, 256, 0, stream>>>(eidx, cursor, elist, E);
  edge_mlp_kernel<<<(E + 127) / 128, 256, 0, stream>>>(eemb, fw1, fw2, fw3, elist, wbuf, E);
  gather_out_kernel<<<(N + 3) / 4, 256, 0, stream>>>(nf, wbuf, y, sc, l2w0, l2w1,
                                                     offsets, elist, eidx, eattr, avgp,
                                                     (float*)d_out, N, E);
}

// Round 17
// 215.872 us; speedup vs baseline: 1.5921x; 1.0345x over previous
//
#include <hip/hip_runtime.h>
#include <math.h>

__device__ __forceinline__ float silu(float x) { return x / (1.0f + __expf(-x)); }

typedef __attribute__((ext_vector_type(8))) short short8v;  // 8 bf16 (4 VGPRs)
typedef __attribute__((ext_vector_type(4))) float f32x4;

__device__ __forceinline__ unsigned short f2bf(float x) {
  unsigned int u = __float_as_uint(x);
  return (unsigned short)((u + 0x8000u) >> 16);
}
__device__ __forceinline__ float bf2f(unsigned short v) {
  return __uint_as_float(((unsigned int)v) << 16);
}

// ---------------- Kernel 1: node precompute via bf16 MFMA (R16 proven) -----
__global__ __launch_bounds__(256) void node_pre_kernel(
    const float* __restrict__ nf, const float* __restrict__ na,
    const float* __restrict__ w0, const float* __restrict__ w1,
    const float* __restrict__ scw0, const float* __restrict__ scw1,
    float* __restrict__ y, float* __restrict__ sc, int N)
{
  __shared__ float nfL[32][132];
  __shared__ __align__(16) char aB[4096];
  __shared__ __align__(16) char wB[32768];
  const int t = threadIdx.x;
  const int n0 = blockIdx.x * 32;
  const int wv = t >> 6, l = t & 63;
  const int lrow = l & 15, lkg = l >> 4;
  const int ann = t >> 3, ac = t & 7;
  const float inv_sqrt32 = 0.17677669529663687f;
  const float sc_norm    = 0.08838834764831843f;  // 1/sqrt(32*4)

  for (int x4 = t; x4 < 1024; x4 += 256) {
    const int nn = x4 >> 5, c4 = x4 & 31;
    const int n = n0 + nn;
    float4 v = make_float4(0.f, 0.f, 0.f, 0.f);
    if (n < N) v = *(const float4*)(nf + (size_t)n * 128 + c4 * 4);
    *(float4*)&nfL[nn][c4 * 4] = v;
  }
  if (t < 128) {
    const int nn = t >> 2, c = t & 3;
    const int n = n0 + nn;
    nfL[nn][128 + c] = (n < N) ? na[(size_t)n * 4 + c] : 0.f;
  }
  for (int x = t; x < 1024; x += 256) {
    const int u = x >> 5, w = x & 31;
    *(unsigned short*)(wB + 0 + w * 128 + (((u >> 3) ^ (w & 7)) * 16) + (u & 7) * 2) = f2bf(w0[x]);
  }
  for (int x = t; x < 1024; x += 256) {
    const int u = x >> 5, w = x & 31;
    *(unsigned short*)(wB + 4096 + w * 128 + (((u >> 3) ^ (w & 7)) * 16) + (u & 7) * 2) = f2bf(w1[x]);
  }
  for (int x = t; x < 8192; x += 256) {
    const int k = x >> 6, c = x & 63;
    const int half = k >> 6, kk = k & 63;
    *(unsigned short*)(wB + 8192 + half * 8192 + c * 128 + (((kk >> 3) ^ (c & 7)) * 16) + (kk & 7) * 2) = f2bf(scw0[x]);
  }
  for (int x = t; x < 4096; x += 256) {
    const int k = x >> 5, c = x & 31;
    const int half = k >> 6, kk = k & 63;
    *(unsigned short*)(wB + 24576 + half * 4096 + c * 128 + (((kk >> 3) ^ (c & 7)) * 16) + (kk & 7) * 2) = f2bf(scw1[x]);
  }
  __syncthreads();

  if (ac < 4) {
    short8v hv;
#pragma unroll
    for (int j = 0; j < 8; ++j) hv[j] = (short)f2bf(nfL[ann][ac * 8 + j]);
    *(short8v*)(aB + ann * 128 + ((ac ^ (ann & 7)) * 16)) = hv;
  }
  __syncthreads();
  {
    const int mt = wv >> 1, nt = wv & 1;
    const int ar = mt * 16 + lrow, br = nt * 16 + lrow;
    const short8v A = *(const short8v*)(aB + ar * 128 + ((lkg ^ (ar & 7)) * 16));
    const short8v B = *(const short8v*)(wB + 0 + br * 128 + ((lkg ^ (br & 7)) * 16));
    f32x4 acc = (f32x4){0.f, 0.f, 0.f, 0.f};
    acc = __builtin_amdgcn_mfma_f32_16x16x32_bf16(A, B, acc, 0, 0, 0);
#pragma unroll
    for (int r = 0; r < 4; ++r) {
      const int nn = mt * 16 + lkg * 4 + r;
      const int n = n0 + nn;
      if (n < N) y[(size_t)n * 128 + nt * 16 + lrow] = acc[r] * inv_sqrt32;
    }
  }
  __syncthreads();

  for (int i = 0; i < 3; ++i) {
    if (ac < 4) {
      short8v hv;
#pragma unroll
      for (int j = 0; j < 8; ++j)
        hv[j] = (short)f2bf(nfL[ann][32 + (ac * 8 + j) * 3 + i]);
      *(short8v*)(aB + ann * 128 + ((ac ^ (ann & 7)) * 16)) = hv;
    }
    __syncthreads();
    {
      const int mt = wv >> 1, nt = wv & 1;
      const int ar = mt * 16 + lrow, br = nt * 16 + lrow;
      const short8v A = *(const short8v*)(aB + ar * 128 + ((lkg ^ (ar & 7)) * 16));
      const short8v B = *(const short8v*)(wB + 4096 + br * 128 + ((lkg ^ (br & 7)) * 16));
      f32x4 acc = (f32x4){0.f, 0.f, 0.f, 0.f};
      acc = __builtin_amdgcn_mfma_f32_16x16x32_bf16(A, B, acc, 0, 0, 0);
#pragma unroll
      for (int r = 0; r < 4; ++r) {
        const int nn = mt * 16 + lkg * 4 + r;
        const int n = n0 + nn;
        if (n < N) y[(size_t)n * 128 + 32 + (nt * 16 + lrow) * 3 + i] = acc[r] * inv_sqrt32;
      }
    }
    __syncthreads();
  }

  {
    f32x4 accS[2] = {(f32x4){0.f,0.f,0.f,0.f}, (f32x4){0.f,0.f,0.f,0.f}};
    const int mt = wv & 1, ntb = (wv >> 1) * 2;
#pragma unroll
    for (int half = 0; half < 2; ++half) {
      {
        short8v hv;
#pragma unroll
        for (int j = 0; j < 8; ++j) {
          const int k = half * 64 + ac * 8 + j;
          hv[j] = (short)f2bf(nfL[ann][k >> 2] * nfL[ann][128 + (k & 3)]);
        }
        *(short8v*)(aB + ann * 128 + ((ac ^ (ann & 7)) * 16)) = hv;
      }
      __syncthreads();
#pragma unroll
      for (int step = 0; step < 2; ++step) {
        const int ar = mt * 16 + lrow;
        const short8v A = *(const short8v*)(aB + ar * 128 + (((step * 4 + lkg) ^ (ar & 7)) * 16));
#pragma unroll
        for (int q = 0; q < 2; ++q) {
          const int br = (ntb + q) * 16 + lrow;
          const short8v B = *(const short8v*)(wB + 8192 + half * 8192 + br * 128 + (((step * 4 + lkg) ^ (br & 7)) * 16));
          accS[q] = __builtin_amdgcn_mfma_f32_16x16x32_bf16(A, B, accS[q], 0, 0, 0);
        }
      }
      __syncthreads();
    }
#pragma unroll
    for (int q = 0; q < 2; ++q) {
#pragma unroll
      for (int r = 0; r < 4; ++r) {
        const int nn = mt * 16 + lkg * 4 + r;
        const int n = n0 + nn;
        if (n < N) sc[(size_t)n * 160 + (ntb + q) * 16 + lrow] = accS[q][r] * sc_norm;
      }
    }
  }

  for (int i = 0; i < 3; ++i) {
    f32x4 acc = (f32x4){0.f, 0.f, 0.f, 0.f};
    const int mt = wv >> 1, nt = wv & 1;
#pragma unroll
    for (int half = 0; half < 2; ++half) {
      {
        short8v hv;
#pragma unroll
        for (int j = 0; j < 8; ++j) {
          const int k = half * 64 + ac * 8 + j;
          hv[j] = (short)f2bf(nfL[ann][32 + (k >> 2) * 3 + i] * nfL[ann][128 + (k & 3)]);
        }
        *(short8v*)(aB + ann * 128 + ((ac ^ (ann & 7)) * 16)) = hv;
      }
      __syncthreads();
#pragma unroll
      for (int step = 0; step < 2; ++step) {
        const int ar = mt * 16 + lrow;
        const short8v A = *(const short8v*)(aB + ar * 128 + (((step * 4 + lkg) ^ (ar & 7)) * 16));
        const int br = nt * 16 + lrow;
        const short8v B = *(const short8v*)(wB + 24576 + half * 4096 + br * 128 + (((step * 4 + lkg) ^ (br & 7)) * 16));
        acc = __builtin_amdgcn_mfma_f32_16x16x32_bf16(A, B, acc, 0, 0, 0);
      }
      __syncthreads();
    }
#pragma unroll
    for (int r = 0; r < 4; ++r) {
      const int nn = mt * 16 + lkg * 4 + r;
      const int n = n0 + nn;
      if (n < N) sc[(size_t)n * 160 + 64 + (nt * 16 + lrow) * 3 + i] = acc[r] * sc_norm;
    }
  }
}

// ---------------- CSR build (unchanged) ----------------
__global__ __launch_bounds__(256) void hist_kernel(const int* __restrict__ eidx,
                                                   int* __restrict__ counts, int E)
{
  const int e = blockIdx.x * 256 + threadIdx.x;
  if (e < E) atomicAdd(&counts[eidx[E + e]], 1);
}

__global__ __launch_bounds__(1024) void scan_kernel(const int* __restrict__ counts,
                                                    int* __restrict__ offsets,
                                                    int* __restrict__ cursor, int N)
{
  __shared__ int part[1024];
  const int t = threadIdx.x;
  const int per = (N + 1023) / 1024;
  const int base = t * per;
  int s = 0;
  for (int k = 0; k < per; ++k) { int idx = base + k; if (idx < N) s += counts[idx]; }
  part[t] = s;
  __syncthreads();
  for (int off = 1; off < 1024; off <<= 1) {
    int v = part[t];
    if (t >= off) v += part[t - off];
    __syncthreads();
    part[t] = v;
    __syncthreads();
  }
  int run = (t == 0) ? 0 : part[t - 1];
  for (int k = 0; k < per; ++k) {
    int idx = base + k;
    if (idx < N) { offsets[idx] = run; cursor[idx] = run; run += counts[idx]; }
  }
  if (t == 1023) offsets[N] = run;
}

__global__ __launch_bounds__(256) void scatter_kernel(const int* __restrict__ eidx,
                                                      int* __restrict__ cursor,
                                                      int* __restrict__ elist, int E)
{
  const int e = blockIdx.x * 256 + threadIdx.x;
  if (e >= E) return;
  const int dst = eidx[E + e];
  const int slot = atomicAdd(&cursor[dst], 1);
  elist[slot] = e;
}

// ---------------- Kernel 2: FUSED edge MLP; layers 2+3 via MFMA; bf16 out --
__global__ __launch_bounds__(256) void edge_mlp_kernel(
    const float* __restrict__ eemb, const float* __restrict__ fw1,
    const float* __restrict__ fw2, const float* __restrict__ fw3,
    const int* __restrict__ elist, unsigned short* __restrict__ wbuf, int E)
{
  __shared__ __align__(16) float w1L[512];     // [k<64][r<8] transposed, f32
  __shared__ __align__(16) char reg1[16384];
  __shared__ __align__(16) char reg2[32768];
  const int t = threadIdx.x;
  const int base = blockIdx.x * 128;

  for (int x = t; x < 512; x += 256)  w1L[x] = fw1[(x & 7) * 64 + (x >> 3)];
  for (int x = t; x < 4096; x += 256) {
    const int k = x >> 6, o = x & 63;
    *(unsigned short*)(reg2 + o * 128 + (((k >> 3) ^ (o & 7)) * 16) + (k & 7) * 2) = f2bf(fw2[x]);
  }

  const int e = t & 127, kg = t >> 7;
  {
    const int slot0 = base + e;
    const int eid = (slot0 < E) ? elist[slot0] : 0;
    const float4 em0 = *(const float4*)(eemb + (size_t)eid * 8);
    const float4 em1 = *(const float4*)(eemb + (size_t)eid * 8 + 4);
    __syncthreads();

    const float inv_sqrt8 = 0.35355339059327373f;
#pragma unroll
    for (int c = 0; c < 4; ++c) {
      short8v hv;
#pragma unroll
      for (int j = 0; j < 8; ++j) {
        const int k = kg * 32 + c * 8 + j;
        const float4 wa = *(const float4*)(w1L + k * 8);
        const float4 wb = *(const float4*)(w1L + k * 8 + 4);
        const float a = em0.x * wa.x + em0.y * wa.y + em0.z * wa.z + em0.w * wa.w
                      + em1.x * wb.x + em1.y * wb.y + em1.z * wb.z + em1.w * wb.w;
        hv[j] = (short)f2bf(silu(a * inv_sqrt8));
      }
      const int cc = kg * 4 + c;
      *(short8v*)(reg1 + e * 128 + ((cc ^ (e & 7)) * 16)) = hv;
    }
  }
  __syncthreads();

  const int wv = t >> 6, l = t & 63;
  const int lrow = l & 15, lkg = l >> 4;

  {
    f32x4 accB[2][4];
#pragma unroll
    for (int mt = 0; mt < 2; ++mt)
#pragma unroll
      for (int nt = 0; nt < 4; ++nt)
        accB[mt][nt] = (f32x4){0.f, 0.f, 0.f, 0.f};

#pragma unroll
    for (int step = 0; step < 2; ++step) {
#pragma unroll
      for (int mt = 0; mt < 2; ++mt) {
        const int ea = wv * 32 + mt * 16 + lrow;
        const short8v A = *(const short8v*)(reg1 + ea * 128 + (((step * 4 + lkg) ^ (ea & 7)) * 16));
#pragma unroll
        for (int nt = 0; nt < 4; ++nt) {
          const int o = nt * 16 + lrow;
          const short8v B = *(const short8v*)(reg2 + o * 128 + (((step * 4 + lkg) ^ (o & 7)) * 16));
          accB[mt][nt] = __builtin_amdgcn_mfma_f32_16x16x32_bf16(A, B, accB[mt][nt], 0, 0, 0);
        }
      }
    }
    __syncthreads();

#pragma unroll
    for (int mt = 0; mt < 2; ++mt) {
#pragma unroll
      for (int r = 0; r < 4; ++r) {
        const int eo = wv * 32 + mt * 16 + lkg * 4 + r;
#pragma unroll
        for (int nt = 0; nt < 4; ++nt) {
          const int o = nt * 16 + lrow;
          const float val = silu(accB[mt][nt][r] * 0.125f);
          *(unsigned short*)(reg1 + eo * 128 + (((o >> 3) ^ (eo & 7)) * 16) + (o & 7) * 2) = f2bf(val);
        }
      }
    }
  }
  for (int x = t; x < 8192; x += 256) {
    const int k = x >> 7, c = x & 127;
    *(unsigned short*)(reg2 + c * 128 + (((k >> 3) ^ (c & 7)) * 16) + (k & 7) * 2) = f2bf(fw3[x]);
  }
  __syncthreads();

  {
    f32x4 accd[2][8];
#pragma unroll
    for (int mt = 0; mt < 2; ++mt)
#pragma unroll
      for (int nt = 0; nt < 8; ++nt)
        accd[mt][nt] = (f32x4){0.f, 0.f, 0.f, 0.f};

#pragma unroll
    for (int step = 0; step < 2; ++step) {
      const int ea0 = wv * 32 + lrow;
      const int ea1 = wv * 32 + 16 + lrow;
      const short8v A0 = *(const short8v*)(reg1 + ea0 * 128 + (((step * 4 + lkg) ^ (ea0 & 7)) * 16));
      const short8v A1 = *(const short8v*)(reg1 + ea1 * 128 + (((step * 4 + lkg) ^ (ea1 & 7)) * 16));
#pragma unroll
      for (int nt = 0; nt < 8; ++nt) {
        const int n = nt * 16 + lrow;
        const short8v B = *(const short8v*)(reg2 + n * 128 + (((step * 4 + lkg) ^ (n & 7)) * 16));
        accd[0][nt] = __builtin_amdgcn_mfma_f32_16x16x32_bf16(A0, B, accd[0][nt], 0, 0, 0);
        accd[1][nt] = __builtin_amdgcn_mfma_f32_16x16x32_bf16(A1, B, accd[1][nt], 0, 0, 0);
      }
    }
#pragma unroll
    for (int mt = 0; mt < 2; ++mt) {
#pragma unroll
      for (int r = 0; r < 4; ++r) {
        const int eo = wv * 32 + mt * 16 + lkg * 4 + r;
        const int slot = base + eo;
        if (slot < E) {
          unsigned short* wrow = wbuf + (size_t)slot * 128 + lrow;
#pragma unroll
          for (int nt = 0; nt < 8; ++nt)
            wrow[nt * 16] = f2bf(accd[mt][nt][r] * 0.125f);
        }
      }
    }
  }
}

// ---------------- Kernel 3: wave-per-node gather (bf16 wbuf, pipelined) ----
__global__ __launch_bounds__(256) void gather_out_kernel(
    const float* __restrict__ nf, const unsigned short* __restrict__ wbuf,
    const float* __restrict__ y, const float* __restrict__ sc,
    const float* __restrict__ l2w0, const float* __restrict__ l2w1,
    const int* __restrict__ offsets, const int* __restrict__ elist,
    const int* __restrict__ eidx, const float* __restrict__ eattr,
    const int* __restrict__ avgp, float* __restrict__ out, int N, int E)
{
  __shared__ float mW[4][264];    // per-wave m[256] (+pad)
  __shared__ float soW[4][160];   // per-wave so0[64] + so1[96]
  const int t = threadIdx.x;
  const int wv = t >> 6, l = t & 63;
  const int n = blockIdx.x * 4 + wv;
  const bool valid = (n < N);
  const int u = l & 31, half = l >> 5;

  const int beg = valid ? offsets[n] : 0;
  const int end = valid ? offsets[n + 1] : 0;

  float s0 = 0.f, s1 = 0.f;
  float v0x = 0.f, v0y = 0.f, v0z = 0.f;
  float v1x = 0.f, v1y = 0.f, v1z = 0.f;

  // 1-ahead pipeline of the index chain: elist -> (eidx, eattr)
  int s = beg + half;
  int srcC = 0; float4 eaC = make_float4(0.f, 0.f, 0.f, 0.f);
  if (s < end) {
    const int eid = elist[s];
    srcC = eidx[eid];
    eaC = *(const float4*)(eattr + (size_t)eid * 4);
  }
  for (; s < end; ) {
    const int s2 = s + 2;
    int srcN = 0; float4 eaN = make_float4(0.f, 0.f, 0.f, 0.f);
    if (s2 < end) {
      const int eid2 = elist[s2];
      srcN = eidx[eid2];
      eaN = *(const float4*)(eattr + (size_t)eid2 * 4);
    }
    const unsigned short* wr = wbuf + (size_t)s * 128;
    const float* yr = y + (size_t)srcC * 128;
    const float w00 = bf2f(wr[u]),      w01 = bf2f(wr[32 + u]);
    const float w10 = bf2f(wr[64 + u]), w11 = bf2f(wr[96 + u]);
    const float g0  = yr[u];
    const float g1x = yr[32 + 3 * u], g1y = yr[33 + 3 * u], g1z = yr[34 + 3 * u];
    s0 += w00 * g0 * eaC.x;
    const float t01 = w01 * g0;
    v0x += t01 * eaC.y; v0y += t01 * eaC.z; v0z += t01 * eaC.w;
    const float wg = w10 * eaC.x;
    v1x += wg * g1x; v1y += wg * g1y; v1z += wg * g1z;
    s1 += w11 * (g1x * eaC.y + g1y * eaC.z + g1z * eaC.w);
    s = s2; srcC = srcN; eaC = eaN;
  }
  s0 += __shfl_xor(s0, 32);  s1 += __shfl_xor(s1, 32);
  v0x += __shfl_xor(v0x, 32); v0y += __shfl_xor(v0y, 32); v0z += __shfl_xor(v0z, 32);
  v1x += __shfl_xor(v1x, 32); v1y += __shfl_xor(v1y, 32); v1z += __shfl_xor(v1z, 32);
  if (half == 0) {
    mW[wv][u]          = s0;
    mW[wv][32 + u]     = s1 * 0.5773502691896258f;
    mW[wv][64 + 3 * u] = v0x; mW[wv][65 + 3 * u] = v0y; mW[wv][66 + 3 * u] = v0z;
    mW[wv][160 + 3 * u] = v1x; mW[wv][161 + 3 * u] = v1y; mW[wv][162 + 3 * u] = v1z;
  }
  __syncthreads();

  const float scl = 0.125f * rsqrtf((float)(*avgp));
  const float* m = mW[wv];
  if (valid) {
    {
      float acc = 0.f;
      for (int uu = 0; uu < 64; ++uu) acc += m[uu] * l2w0[uu * 64 + l];
      soW[wv][l] = acc * scl + sc[(size_t)n * 160 + l];
    }
    {
      const int w = l / 3, i = l - 3 * w;
      float acc = 0.f;
      for (int uu = 0; uu < 64; ++uu) acc += m[64 + uu * 3 + i] * l2w1[uu * 32 + w];
      soW[wv][64 + l] = acc * scl + sc[(size_t)n * 160 + 64 + l];
    }
    if (l < 32) {
      const int q = 64 + l, w = q / 3, i = q - 3 * w;
      float acc = 0.f;
      for (int uu = 0; uu < 64; ++uu) acc += m[64 + uu * 3 + i] * l2w1[uu * 32 + w];
      soW[wv][64 + q] = acc * scl + sc[(size_t)n * 160 + 64 + q];
    }
  }
  __syncthreads();

  if (valid) {
#pragma unroll
    for (int p = 0; p < 2; ++p) {
      const int c = p * 64 + l;
      float val;
      if (c < 32) {
        val = silu(soW[wv][c]);
      } else {
        const int q = c - 32, w = q / 3, i = q - 3 * w;
        val = silu(soW[wv][32 + w]) * soW[wv][64 + w * 3 + i];
      }
      out[(size_t)n * 128 + c] = nf[(size_t)n * 128 + c] + val;
    }
  }
}

extern "C" void kernel_launch(void* const* d_in, const int* in_sizes, int n_in,
                              void* d_out, int out_size, void* d_ws, size_t ws_size,
                              hipStream_t stream)
{
  const float* nf    = (const float*)d_in[0];
  const float* na    = (const float*)d_in[1];
  const float* eattr = (const float*)d_in[2];
  const float* eemb  = (const float*)d_in[3];
  const float* l1w0  = (const float*)d_in[4];
  const float* l1w1  = (const float*)d_in[5];
  const float* fw1   = (const float*)d_in[6];
  const float* fw2   = (const float*)d_in[7];
  const float* fw3   = (const float*)d_in[8];
  const float* l2w0  = (const float*)d_in[9];
  const float* l2w1  = (const float*)d_in[10];
  const float* scw0  = (const float*)d_in[11];
  const float* scw1  = (const float*)d_in[12];
  const int*   eidx  = (const int*)d_in[13];
  const int*   avgp  = (const int*)d_in[14];

  const int N = in_sizes[0] / 128;
  const int E = in_sizes[2] / 4;

  // Same byte layout as R3-R16 (wbuf region reused as bf16, uses half).
  float* y       = (float*)d_ws;                    // N*128
  float* sc      = y + (size_t)N * 128;             // N*160
  float* wbuff   = sc + (size_t)N * 160;            // E*128 floats reserved
  unsigned short* wbuf = (unsigned short*)wbuff;    // used as E*128 bf16
  int*   counts  = (int*)(wbuff + (size_t)E * 128); // N
  int*   offsets = counts + N;                      // N+1
  int*   cursor  = offsets + N + 1;                 // N
  int*   elist   = cursor + N;                      // E (slot -> eid)

  hipMemsetAsync(counts, 0, (size_t)N * sizeof(int), stream);
  node_pre_kernel<<<(N + 31) / 32, 256, 0, stream>>>(nf, na, l1w0, l1w1, scw0, scw1, y, sc, N);
  hist_kernel<<<(E + 255) / 256, 256, 0, stream>>>(eidx, counts, E);
  scan_kernel<<<1, 1024, 0, stream>>>(counts, offsets, cursor, N);
  scatter_kernel<<<(E + 255) / 256, 256, 0, stream>>>(eidx, cursor, elist, E);
  edge_mlp_kernel<<<(E + 127) / 128, 256, 0, stream>>>(eemb, fw1, fw2, fw3, elist, wbuf, E);
  gather_out_kernel<<<(N + 3) / 4, 256, 0, stream>>>(nf, wbuf, y, sc, l2w0, l2w1,
                                                     offsets, elist, eidx, eattr, avgp,
                                                     (float*)d_out, N, E);
}

// Round 18
// 210.233 us; speedup vs baseline: 1.6349x; 1.0268x over previous
//
#include <hip/hip_runtime.h>
#include <math.h>

__device__ __forceinline__ float silu(float x) { return x / (1.0f + __expf(-x)); }

typedef __attribute__((ext_vector_type(8))) short short8v;  // 8 bf16 (4 VGPRs)
typedef __attribute__((ext_vector_type(4))) float f32x4;

__device__ __forceinline__ unsigned short f2bf(float x) {
  unsigned int u = __float_as_uint(x);
  return (unsigned short)((u + 0x8000u) >> 16);
}
__device__ __forceinline__ float bf2f(unsigned short v) {
  return __uint_as_float(((unsigned int)v) << 16);
}

// ---------------- Kernel 1: node precompute via bf16 MFMA (R16 proven) -----
__global__ __launch_bounds__(256) void node_pre_kernel(
    const float* __restrict__ nf, const float* __restrict__ na,
    const float* __restrict__ w0, const float* __restrict__ w1,
    const float* __restrict__ scw0, const float* __restrict__ scw1,
    float* __restrict__ y, float* __restrict__ sc, int N)
{
  __shared__ float nfL[32][132];
  __shared__ __align__(16) char aB[4096];
  __shared__ __align__(16) char wB[32768];
  const int t = threadIdx.x;
  const int n0 = blockIdx.x * 32;
  const int wv = t >> 6, l = t & 63;
  const int lrow = l & 15, lkg = l >> 4;
  const int ann = t >> 3, ac = t & 7;
  const float inv_sqrt32 = 0.17677669529663687f;
  const float sc_norm    = 0.08838834764831843f;  // 1/sqrt(32*4)

  for (int x4 = t; x4 < 1024; x4 += 256) {
    const int nn = x4 >> 5, c4 = x4 & 31;
    const int n = n0 + nn;
    float4 v = make_float4(0.f, 0.f, 0.f, 0.f);
    if (n < N) v = *(const float4*)(nf + (size_t)n * 128 + c4 * 4);
    *(float4*)&nfL[nn][c4 * 4] = v;
  }
  if (t < 128) {
    const int nn = t >> 2, c = t & 3;
    const int n = n0 + nn;
    nfL[nn][128 + c] = (n < N) ? na[(size_t)n * 4 + c] : 0.f;
  }
  for (int x = t; x < 1024; x += 256) {
    const int u = x >> 5, w = x & 31;
    *(unsigned short*)(wB + 0 + w * 128 + (((u >> 3) ^ (w & 7)) * 16) + (u & 7) * 2) = f2bf(w0[x]);
  }
  for (int x = t; x < 1024; x += 256) {
    const int u = x >> 5, w = x & 31;
    *(unsigned short*)(wB + 4096 + w * 128 + (((u >> 3) ^ (w & 7)) * 16) + (u & 7) * 2) = f2bf(w1[x]);
  }
  for (int x = t; x < 8192; x += 256) {
    const int k = x >> 6, c = x & 63;
    const int half = k >> 6, kk = k & 63;
    *(unsigned short*)(wB + 8192 + half * 8192 + c * 128 + (((kk >> 3) ^ (c & 7)) * 16) + (kk & 7) * 2) = f2bf(scw0[x]);
  }
  for (int x = t; x < 4096; x += 256) {
    const int k = x >> 5, c = x & 31;
    const int half = k >> 6, kk = k & 63;
    *(unsigned short*)(wB + 24576 + half * 4096 + c * 128 + (((kk >> 3) ^ (c & 7)) * 16) + (kk & 7) * 2) = f2bf(scw1[x]);
  }
  __syncthreads();

  if (ac < 4) {
    short8v hv;
#pragma unroll
    for (int j = 0; j < 8; ++j) hv[j] = (short)f2bf(nfL[ann][ac * 8 + j]);
    *(short8v*)(aB + ann * 128 + ((ac ^ (ann & 7)) * 16)) = hv;
  }
  __syncthreads();
  {
    const int mt = wv >> 1, nt = wv & 1;
    const int ar = mt * 16 + lrow, br = nt * 16 + lrow;
    const short8v A = *(const short8v*)(aB + ar * 128 + ((lkg ^ (ar & 7)) * 16));
    const short8v B = *(const short8v*)(wB + 0 + br * 128 + ((lkg ^ (br & 7)) * 16));
    f32x4 acc = (f32x4){0.f, 0.f, 0.f, 0.f};
    acc = __builtin_amdgcn_mfma_f32_16x16x32_bf16(A, B, acc, 0, 0, 0);
#pragma unroll
    for (int r = 0; r < 4; ++r) {
      const int nn = mt * 16 + lkg * 4 + r;
      const int n = n0 + nn;
      if (n < N) y[(size_t)n * 128 + nt * 16 + lrow] = acc[r] * inv_sqrt32;
    }
  }
  __syncthreads();

  for (int i = 0; i < 3; ++i) {
    if (ac < 4) {
      short8v hv;
#pragma unroll
      for (int j = 0; j < 8; ++j)
        hv[j] = (short)f2bf(nfL[ann][32 + (ac * 8 + j) * 3 + i]);
      *(short8v*)(aB + ann * 128 + ((ac ^ (ann & 7)) * 16)) = hv;
    }
    __syncthreads();
    {
      const int mt = wv >> 1, nt = wv & 1;
      const int ar = mt * 16 + lrow, br = nt * 16 + lrow;
      const short8v A = *(const short8v*)(aB + ar * 128 + ((lkg ^ (ar & 7)) * 16));
      const short8v B = *(const short8v*)(wB + 4096 + br * 128 + ((lkg ^ (br & 7)) * 16));
      f32x4 acc = (f32x4){0.f, 0.f, 0.f, 0.f};
      acc = __builtin_amdgcn_mfma_f32_16x16x32_bf16(A, B, acc, 0, 0, 0);
#pragma unroll
      for (int r = 0; r < 4; ++r) {
        const int nn = mt * 16 + lkg * 4 + r;
        const int n = n0 + nn;
        if (n < N) y[(size_t)n * 128 + 32 + (nt * 16 + lrow) * 3 + i] = acc[r] * inv_sqrt32;
      }
    }
    __syncthreads();
  }

  {
    f32x4 accS[2] = {(f32x4){0.f,0.f,0.f,0.f}, (f32x4){0.f,0.f,0.f,0.f}};
    const int mt = wv & 1, ntb = (wv >> 1) * 2;
#pragma unroll
    for (int half = 0; half < 2; ++half) {
      {
        short8v hv;
#pragma unroll
        for (int j = 0; j < 8; ++j) {
          const int k = half * 64 + ac * 8 + j;
          hv[j] = (short)f2bf(nfL[ann][k >> 2] * nfL[ann][128 + (k & 3)]);
        }
        *(short8v*)(aB + ann * 128 + ((ac ^ (ann & 7)) * 16)) = hv;
      }
      __syncthreads();
#pragma unroll
      for (int step = 0; step < 2; ++step) {
        const int ar = mt * 16 + lrow;
        const short8v A = *(const short8v*)(aB + ar * 128 + (((step * 4 + lkg) ^ (ar & 7)) * 16));
#pragma unroll
        for (int q = 0; q < 2; ++q) {
          const int br = (ntb + q) * 16 + lrow;
          const short8v B = *(const short8v*)(wB + 8192 + half * 8192 + br * 128 + (((step * 4 + lkg) ^ (br & 7)) * 16));
          accS[q] = __builtin_amdgcn_mfma_f32_16x16x32_bf16(A, B, accS[q], 0, 0, 0);
        }
      }
      __syncthreads();
    }
#pragma unroll
    for (int q = 0; q < 2; ++q) {
#pragma unroll
      for (int r = 0; r < 4; ++r) {
        const int nn = mt * 16 + lkg * 4 + r;
        const int n = n0 + nn;
        if (n < N) sc[(size_t)n * 160 + (ntb + q) * 16 + lrow] = accS[q][r] * sc_norm;
      }
    }
  }

  for (int i = 0; i < 3; ++i) {
    f32x4 acc = (f32x4){0.f, 0.f, 0.f, 0.f};
    const int mt = wv >> 1, nt = wv & 1;
#pragma unroll
    for (int half = 0; half < 2; ++half) {
      {
        short8v hv;
#pragma unroll
        for (int j = 0; j < 8; ++j) {
          const int k = half * 64 + ac * 8 + j;
          hv[j] = (short)f2bf(nfL[ann][32 + (k >> 2) * 3 + i] * nfL[ann][128 + (k & 3)]);
        }
        *(short8v*)(aB + ann * 128 + ((ac ^ (ann & 7)) * 16)) = hv;
      }
      __syncthreads();
#pragma unroll
      for (int step = 0; step < 2; ++step) {
        const int ar = mt * 16 + lrow;
        const short8v A = *(const short8v*)(aB + ar * 128 + (((step * 4 + lkg) ^ (ar & 7)) * 16));
        const int br = nt * 16 + lrow;
        const short8v B = *(const short8v*)(wB + 24576 + half * 4096 + br * 128 + (((step * 4 + lkg) ^ (br & 7)) * 16));
        acc = __builtin_amdgcn_mfma_f32_16x16x32_bf16(A, B, acc, 0, 0, 0);
      }
      __syncthreads();
    }
#pragma unroll
    for (int r = 0; r < 4; ++r) {
      const int nn = mt * 16 + lkg * 4 + r;
      const int n = n0 + nn;
      if (n < N) sc[(size_t)n * 160 + 64 + (nt * 16 + lrow) * 3 + i] = acc[r] * sc_norm;
    }
  }
}

// ---------------- CSR build ----------------
__global__ __launch_bounds__(256) void hist_kernel(const int* __restrict__ eidx,
                                                   int* __restrict__ counts, int E)
{
  const int e = blockIdx.x * 256 + threadIdx.x;
  if (e < E) atomicAdd(&counts[eidx[E + e]], 1);
}

__global__ __launch_bounds__(1024) void scan_kernel(const int* __restrict__ counts,
                                                    int* __restrict__ offsets,
                                                    int* __restrict__ cursor, int N)
{
  __shared__ int part[1024];
  const int t = threadIdx.x;
  const int per = (N + 1023) / 1024;
  const int base = t * per;
  int s = 0;
  for (int k = 0; k < per; ++k) { int idx = base + k; if (idx < N) s += counts[idx]; }
  part[t] = s;
  __syncthreads();
  for (int off = 1; off < 1024; off <<= 1) {
    int v = part[t];
    if (t >= off) v += part[t - off];
    __syncthreads();
    part[t] = v;
    __syncthreads();
  }
  int run = (t == 0) ? 0 : part[t - 1];
  for (int k = 0; k < per; ++k) {
    int idx = base + k;
    if (idx < N) { offsets[idx] = run; cursor[idx] = run; run += counts[idx]; }
  }
  if (t == 1023) offsets[N] = run;
}

// Scatter also materializes slot-ordered src + eattr (kills gather indirection).
__global__ __launch_bounds__(256) void scatter_kernel(
    const int* __restrict__ eidx, const float* __restrict__ eattr,
    int* __restrict__ cursor, int* __restrict__ elist,
    int* __restrict__ srcS, float4* __restrict__ eaS, int E)
{
  const int e = blockIdx.x * 256 + threadIdx.x;
  if (e >= E) return;
  const int dst = eidx[E + e];
  const int slot = atomicAdd(&cursor[dst], 1);
  elist[slot] = e;
  srcS[slot] = eidx[e];
  eaS[slot] = *(const float4*)(eattr + (size_t)e * 4);
}

// ---------------- Kernel 2: FUSED edge MLP; layers 2+3 via MFMA; bf16 out --
__global__ __launch_bounds__(256) void edge_mlp_kernel(
    const float* __restrict__ eemb, const float* __restrict__ fw1,
    const float* __restrict__ fw2, const float* __restrict__ fw3,
    const int* __restrict__ elist, unsigned short* __restrict__ wbuf, int E)
{
  __shared__ __align__(16) float w1L[512];     // [k<64][r<8] transposed, f32
  __shared__ __align__(16) char reg1[16384];
  __shared__ __align__(16) char reg2[32768];
  const int t = threadIdx.x;
  const int base = blockIdx.x * 128;

  for (int x = t; x < 512; x += 256)  w1L[x] = fw1[(x & 7) * 64 + (x >> 3)];
  for (int x = t; x < 4096; x += 256) {
    const int k = x >> 6, o = x & 63;
    *(unsigned short*)(reg2 + o * 128 + (((k >> 3) ^ (o & 7)) * 16) + (k & 7) * 2) = f2bf(fw2[x]);
  }

  const int e = t & 127, kg = t >> 7;
  {
    const int slot0 = base + e;
    const int eid = (slot0 < E) ? elist[slot0] : 0;
    const float4 em0 = *(const float4*)(eemb + (size_t)eid * 8);
    const float4 em1 = *(const float4*)(eemb + (size_t)eid * 8 + 4);
    __syncthreads();

    const float inv_sqrt8 = 0.35355339059327373f;
#pragma unroll
    for (int c = 0; c < 4; ++c) {
      short8v hv;
#pragma unroll
      for (int j = 0; j < 8; ++j) {
        const int k = kg * 32 + c * 8 + j;
        const float4 wa = *(const float4*)(w1L + k * 8);
        const float4 wb = *(const float4*)(w1L + k * 8 + 4);
        const float a = em0.x * wa.x + em0.y * wa.y + em0.z * wa.z + em0.w * wa.w
                      + em1.x * wb.x + em1.y * wb.y + em1.z * wb.z + em1.w * wb.w;
        hv[j] = (short)f2bf(silu(a * inv_sqrt8));
      }
      const int cc = kg * 4 + c;
      *(short8v*)(reg1 + e * 128 + ((cc ^ (e & 7)) * 16)) = hv;
    }
  }
  __syncthreads();

  const int wv = t >> 6, l = t & 63;
  const int lrow = l & 15, lkg = l >> 4;

  {
    f32x4 accB[2][4];
#pragma unroll
    for (int mt = 0; mt < 2; ++mt)
#pragma unroll
      for (int nt = 0; nt < 4; ++nt)
        accB[mt][nt] = (f32x4){0.f, 0.f, 0.f, 0.f};

#pragma unroll
    for (int step = 0; step < 2; ++step) {
#pragma unroll
      for (int mt = 0; mt < 2; ++mt) {
        const int ea = wv * 32 + mt * 16 + lrow;
        const short8v A = *(const short8v*)(reg1 + ea * 128 + (((step * 4 + lkg) ^ (ea & 7)) * 16));
#pragma unroll
        for (int nt = 0; nt < 4; ++nt) {
          const int o = nt * 16 + lrow;
          const short8v B = *(const short8v*)(reg2 + o * 128 + (((step * 4 + lkg) ^ (o & 7)) * 16));
          accB[mt][nt] = __builtin_amdgcn_mfma_f32_16x16x32_bf16(A, B, accB[mt][nt], 0, 0, 0);
        }
      }
    }
    __syncthreads();

#pragma unroll
    for (int mt = 0; mt < 2; ++mt) {
#pragma unroll
      for (int r = 0; r < 4; ++r) {
        const int eo = wv * 32 + mt * 16 + lkg * 4 + r;
#pragma unroll
        for (int nt = 0; nt < 4; ++nt) {
          const int o = nt * 16 + lrow;
          const float val = silu(accB[mt][nt][r] * 0.125f);
          *(unsigned short*)(reg1 + eo * 128 + (((o >> 3) ^ (eo & 7)) * 16) + (o & 7) * 2) = f2bf(val);
        }
      }
    }
  }
  for (int x = t; x < 8192; x += 256) {
    const int k = x >> 7, c = x & 127;
    *(unsigned short*)(reg2 + c * 128 + (((k >> 3) ^ (c & 7)) * 16) + (k & 7) * 2) = f2bf(fw3[x]);
  }
  __syncthreads();

  {
    f32x4 accd[2][8];
#pragma unroll
    for (int mt = 0; mt < 2; ++mt)
#pragma unroll
      for (int nt = 0; nt < 8; ++nt)
        accd[mt][nt] = (f32x4){0.f, 0.f, 0.f, 0.f};

#pragma unroll
    for (int step = 0; step < 2; ++step) {
      const int ea0 = wv * 32 + lrow;
      const int ea1 = wv * 32 + 16 + lrow;
      const short8v A0 = *(const short8v*)(reg1 + ea0 * 128 + (((step * 4 + lkg) ^ (ea0 & 7)) * 16));
      const short8v A1 = *(const short8v*)(reg1 + ea1 * 128 + (((step * 4 + lkg) ^ (ea1 & 7)) * 16));
#pragma unroll
      for (int nt = 0; nt < 8; ++nt) {
        const int n = nt * 16 + lrow;
        const short8v B = *(const short8v*)(reg2 + n * 128 + (((step * 4 + lkg) ^ (n & 7)) * 16));
        accd[0][nt] = __builtin_amdgcn_mfma_f32_16x16x32_bf16(A0, B, accd[0][nt], 0, 0, 0);
        accd[1][nt] = __builtin_amdgcn_mfma_f32_16x16x32_bf16(A1, B, accd[1][nt], 0, 0, 0);
      }
    }
#pragma unroll
    for (int mt = 0; mt < 2; ++mt) {
#pragma unroll
      for (int r = 0; r < 4; ++r) {
        const int eo = wv * 32 + mt * 16 + lkg * 4 + r;
        const int slot = base + eo;
        if (slot < E) {
          unsigned short* wrow = wbuf + (size_t)slot * 128 + lrow;
#pragma unroll
          for (int nt = 0; nt < 8; ++nt)
            wrow[nt * 16] = f2bf(accd[mt][nt][r] * 0.125f);
        }
      }
    }
  }
}

// ---------------- Kernel 3: wave-per-node gather, zero-indirection streams --
__global__ __launch_bounds__(256) void gather_out_kernel(
    const float* __restrict__ nf, const unsigned short* __restrict__ wbuf,
    const float* __restrict__ y, const float* __restrict__ sc,
    const float* __restrict__ l2w0, const float* __restrict__ l2w1,
    const int* __restrict__ offsets, const int* __restrict__ srcS,
    const float4* __restrict__ eaS,
    const int* __restrict__ avgp, float* __restrict__ out, int N, int E)
{
  __shared__ float mW[4][264];    // per-wave m[256] (+pad)
  __shared__ float soW[4][160];   // per-wave so0[64] + so1[96]
  const int t = threadIdx.x;
  const int wv = t >> 6, l = t & 63;
  const int n = blockIdx.x * 4 + wv;
  const bool valid = (n < N);
  const int u = l & 31, half = l >> 5;

  const int beg = valid ? offsets[n] : 0;
  const int end = valid ? offsets[n + 1] : 0;

  float s0 = 0.f, s1 = 0.f;
  float v0x = 0.f, v0y = 0.f, v0z = 0.f;
  float v1x = 0.f, v1y = 0.f, v1z = 0.f;

  // 1-ahead pipeline on the only remaining chain: srcS -> y
  int s = beg + half;
  int srcC = 0; float4 eaC = make_float4(0.f, 0.f, 0.f, 0.f);
  if (s < end) { srcC = srcS[s]; eaC = eaS[s]; }
  for (; s < end; ) {
    const int s2 = s + 2;
    int srcN = 0; float4 eaN = make_float4(0.f, 0.f, 0.f, 0.f);
    if (s2 < end) { srcN = srcS[s2]; eaN = eaS[s2]; }
    const unsigned short* wr = wbuf + (size_t)s * 128;
    const float* yr = y + (size_t)srcC * 128;
    const float w00 = bf2f(wr[u]),      w01 = bf2f(wr[32 + u]);
    const float w10 = bf2f(wr[64 + u]), w11 = bf2f(wr[96 + u]);
    const float g0  = yr[u];
    const float g1x = yr[32 + 3 * u], g1y = yr[33 + 3 * u], g1z = yr[34 + 3 * u];
    s0 += w00 * g0 * eaC.x;
    const float t01 = w01 * g0;
    v0x += t01 * eaC.y; v0y += t01 * eaC.z; v0z += t01 * eaC.w;
    const float wg = w10 * eaC.x;
    v1x += wg * g1x; v1y += wg * g1y; v1z += wg * g1z;
    s1 += w11 * (g1x * eaC.y + g1y * eaC.z + g1z * eaC.w);
    s = s2; srcC = srcN; eaC = eaN;
  }
  s0 += __shfl_xor(s0, 32);  s1 += __shfl_xor(s1, 32);
  v0x += __shfl_xor(v0x, 32); v0y += __shfl_xor(v0y, 32); v0z += __shfl_xor(v0z, 32);
  v1x += __shfl_xor(v1x, 32); v1y += __shfl_xor(v1y, 32); v1z += __shfl_xor(v1z, 32);
  if (half == 0) {
    mW[wv][u]          = s0;
    mW[wv][32 + u]     = s1 * 0.5773502691896258f;
    mW[wv][64 + 3 * u] = v0x; mW[wv][65 + 3 * u] = v0y; mW[wv][66 + 3 * u] = v0z;
    mW[wv][160 + 3 * u] = v1x; mW[wv][161 + 3 * u] = v1y; mW[wv][162 + 3 * u] = v1z;
  }
  __syncthreads();

  const float scl = 0.125f * rsqrtf((float)(*avgp));
  const float* m = mW[wv];
  if (valid) {
    {
      float acc = 0.f;
      for (int uu = 0; uu < 64; ++uu) acc += m[uu] * l2w0[uu * 64 + l];
      soW[wv][l] = acc * scl + sc[(size_t)n * 160 + l];
    }
    {
      const int w = l / 3, i = l - 3 * w;
      float acc = 0.f;
      for (int uu = 0; uu < 64; ++uu) acc += m[64 + uu * 3 + i] * l2w1[uu * 32 + w];
      soW[wv][64 + l] = acc * scl + sc[(size_t)n * 160 + 64 + l];
    }
    if (l < 32) {
      const int q = 64 + l, w = q / 3, i = q - 3 * w;
      float acc = 0.f;
      for (int uu = 0; uu < 64; ++uu) acc += m[64 + uu * 3 + i] * l2w1[uu * 32 + w];
      soW[wv][64 + q] = acc * scl + sc[(size_t)n * 160 + 64 + q];
    }
  }
  __syncthreads();

  if (valid) {
#pragma unroll
    for (int p = 0; p < 2; ++p) {
      const int c = p * 64 + l;
      float val;
      if (c < 32) {
        val = silu(soW[wv][c]);
      } else {
        const int q = c - 32, w = q / 3, i = q - 3 * w;
        val = silu(soW[wv][32 + w]) * soW[wv][64 + w * 3 + i];
      }
      out[(size_t)n * 128 + c] = nf[(size_t)n * 128 + c] + val;
    }
  }
}

extern "C" void kernel_launch(void* const* d_in, const int* in_sizes, int n_in,
                              void* d_out, int out_size, void* d_ws, size_t ws_size,
                              hipStream_t stream)
{
  const float* nf    = (const float*)d_in[0];
  const float* na    = (const float*)d_in[1];
  const float* eattr = (const float*)d_in[2];
  const float* eemb  = (const float*)d_in[3];
  const float* l1w0  = (const float*)d_in[4];
  const float* l1w1  = (const float*)d_in[5];
  const float* fw1   = (const float*)d_in[6];
  const float* fw2   = (const float*)d_in[7];
  const float* fw3   = (const float*)d_in[8];
  const float* l2w0  = (const float*)d_in[9];
  const float* l2w1  = (const float*)d_in[10];
  const float* scw0  = (const float*)d_in[11];
  const float* scw1  = (const float*)d_in[12];
  const int*   eidx  = (const int*)d_in[13];
  const int*   avgp  = (const int*)d_in[14];

  const int N = in_sizes[0] / 128;
  const int E = in_sizes[2] / 4;

  // Same footprint as R3-R17: wbuf region (E*128 floats) holds bf16 wbuf
  // (first E*64 floats) + slot-ordered srcS (E ints) + eaS (E float4).
  float* y       = (float*)d_ws;                    // N*128
  float* sc      = y + (size_t)N * 128;             // N*160
  float* wbuff   = sc + (size_t)N * 160;            // E*128 floats reserved
  unsigned short* wbuf = (unsigned short*)wbuff;    // E*128 bf16 (= E*64 floats)
  int*    srcS   = (int*)(wbuff + (size_t)E * 64);  // E ints
  float4* eaS    = (float4*)(wbuff + (size_t)E * 64 + E);  // E float4 (16B-aligned)
  int*   counts  = (int*)(wbuff + (size_t)E * 128); // N
  int*   offsets = counts + N;                      // N+1
  int*   cursor  = offsets + N + 1;                 // N
  int*   elist   = cursor + N;                      // E (slot -> eid)

  hipMemsetAsync(counts, 0, (size_t)N * sizeof(int), stream);
  node_pre_kernel<<<(N + 31) / 32, 256, 0, stream>>>(nf, na, l1w0, l1w1, scw0, scw1, y, sc, N);
  hist_kernel<<<(E + 255) / 256, 256, 0, stream>>>(eidx, counts, E);
  scan_kernel<<<1, 1024, 0, stream>>>(counts, offsets, cursor, N);
  scatter_kernel<<<(E + 255) / 256, 256, 0, stream>>>(eidx, eattr, cursor, elist, srcS, eaS, E);
  edge_mlp_kernel<<<(E + 127) / 128, 256, 0, stream>>>(eemb, fw1, fw2, fw3, elist, wbuf, E);
  gather_out_kernel<<<(N + 3) / 4, 256, 0, stream>>>(nf, wbuf, y, sc, l2w0, l2w1,
                                                     offsets, srcS, eaS, avgp,
                                                     (float*)d_out, N, E);
}